// Round 7
// baseline (899.598 us; speedup 1.0000x reference)
//
#include <hip/hip_runtime.h>
#include <hip/hip_bf16.h>
#include <math.h>

// ---------- dims ----------
#define BATCH 17
#define T_EX 16
#define H0 383
#define W0 287
#define C1 64
#define H1 95
#define W1 71
#define H1P 47
#define W1P 35
#define C2 192
#define H2P 23
#define W2P 17
#define C3 384
#define C45 256
#define H5P 11
#define W5P 8
#define DD 256
#define MM 88
#define TM 1408

#define HP1 389
#define WP1 292

typedef unsigned short ushort_t;
typedef __attribute__((ext_vector_type(8))) short short8;
typedef __attribute__((ext_vector_type(4))) float f32x4;

__device__ __forceinline__ float lrelu(float v) { return v > 0.f ? v : 0.01f * v; }

__device__ __forceinline__ ushort_t f2bf(float f) {
    unsigned int u = __float_as_uint(f);
    unsigned int r = (u + 0x7fffu + ((u >> 16) & 1u)) >> 16;
    return (ushort_t)r;
}
__device__ __forceinline__ float b2f(ushort_t b) {
    return __uint_as_float(((unsigned int)b) << 16);
}

__device__ __forceinline__ short8 ld16(const ushort_t* p) {
    return *(const short8*)p;
}
__device__ __forceinline__ short8 ld2x8(const ushort_t* p) {
    union { uint2 u[2]; short8 s; } uu;
    uu.u[0] = *(const uint2*)p;
    uu.u[1] = *(const uint2*)(p + 4);
    return uu.s;
}

// ---------- zero fill ----------
__global__ void zfill_k(float4* __restrict__ p, int n4) {
    int idx = blockIdx.x * 256 + threadIdx.x;
    if (idx < n4) p[idx] = (float4){0.f, 0.f, 0.f, 0.f};
}

// ---------- conv1 input prep: fp32 NCHW -> bf16 NHWC padded (C=4, pad 2) ----------
__global__ void prep1_k(const float* __restrict__ search, const float* __restrict__ exemp,
                        ushort_t* __restrict__ out) {
    int idx = blockIdx.x * 256 + threadIdx.x;
    if (idx >= BATCH * H0 * W0) return;
    int ix = idx % W0; int t = idx / W0;
    int iy = t % H0; int b = t / H0;
    const float* src = (b == 0) ? search : exemp + (size_t)(b - 1) * 3 * H0 * W0;
    const int hw = H0 * W0;
    float v0 = src[iy * W0 + ix];
    float v1 = src[hw + iy * W0 + ix];
    float v2 = src[2 * hw + iy * W0 + ix];
    ushort4 o;
    o.x = f2bf(v0); o.y = f2bf(v1); o.z = f2bf(v2); o.w = 0;
    *(ushort4*)&out[(((size_t)b * HP1 + iy + 2) * WP1 + ix + 2) * 4] = o;
}

// ---------- conv weight prep: OIHW fp32 -> bf16 row-major [oc][Kpad], K-order (ky,kx,ic) ----------
__global__ void wprep_k(const float* __restrict__ w, ushort_t* __restrict__ out,
                        int KH, int KWl, int KWr, int CINl, int CINr,
                        int Kpad8, int nch) {
    int idx = blockIdx.x * 256 + threadIdx.x;
    if (idx >= nch) return;
    int oc = idx / Kpad8;
    int c8 = idx - oc * Kpad8;
    int KWC = KWl * CINl;
    ushort_t* o = out + (size_t)idx * 8;
#pragma unroll
    for (int j = 0; j < 8; ++j) {
        int kg = c8 * 8 + j;
        int ky = kg / KWC; int rem = kg - ky * KWC;
        int kx = rem / CINl; int ic = rem - kx * CINl;
        float v = 0.f;
        if (ky < KH && kx < KWr && ic < CINr)
            v = w[(((size_t)oc * CINr + ic) * KH + ky) * KWr + kx];
        o[j] = f2bf(v);
    }
}

// ---------- generic GEMM weight prep -> row-major [oc][Kpad] ----------
// MODE 0: A[oc][kg] = src[oc*sa + kg*sk];  MODE 1 (cdv): A[c][dk*256+i] = src[c*768+i*3+dk]
template <int MODE>
__global__ void wprep2_k(const float* __restrict__ src, ushort_t* __restrict__ out,
                         int sa, int sk, int Kpad8, int nch) {
    int idx = blockIdx.x * 256 + threadIdx.x;
    if (idx >= nch) return;
    int oc = idx / Kpad8;
    int c8 = idx - oc * Kpad8;
    ushort_t* o = out + (size_t)idx * 8;
#pragma unroll
    for (int j = 0; j < 8; ++j) {
        int kg = c8 * 8 + j;
        float v;
        if (MODE == 0) v = src[(size_t)oc * sa + (size_t)kg * sk];
        else           v = src[(size_t)oc * 768 + (kg & 255) * 3 + (kg >> 8)];
        o[j] = f2bf(v);
    }
}

// ====================================================================
// LDS-free bf16 MFMA implicit-GEMM conv: fragments loaded DIRECT from
// global (A row-major weights, B via NHWC + offset table). No barriers
// in the K-loop; 2-stage register prefetch.
// ====================================================================
template <int STRIDE, bool A16>
__global__ __launch_bounds__(256) void conv_dmfma(
    const ushort_t* __restrict__ inp, const ushort_t* __restrict__ wt,
    const float* __restrict__ bias, ushort_t* __restrict__ out,
    int Hp, int Wp, int C, int Wout, int HW, int NKS, int KWl,
    int OHp, int OWp, int OPAD, int COUT) {
    const int tid = threadIdx.x;
    const int wv = tid >> 6, lane = tid & 63;
    const int quad = lane >> 4, l16 = lane & 15;
    const int n_blk = blockIdx.x * 64;
    const int ocb = blockIdx.y;
    const int b = blockIdx.z;

    __shared__ int offs[448];
    const int KWC = KWl * C;
    for (int g = tid; g < NKS * 4; g += 256) {
        int kg = g * 8;
        int ky = kg / KWC; int rem = kg - ky * KWC;
        int kx = rem / C; int c8 = rem - kx * C;
        offs[g] = (ky * Wp + kx) * C + c8;
    }

    const int Kpad = NKS * 32;
    const ushort_t* inb = inp + (size_t)b * Hp * Wp * C;
    int bbase[4];
#pragma unroll
    for (int cn = 0; cn < 4; ++cn) {
        int n = n_blk + cn * 16 + l16;
        if (n >= HW) n = HW - 1;
        int oy = n / Wout, ox = n - oy * Wout;
        bbase[cn] = (oy * STRIDE * Wp + ox * STRIDE) * C;
    }
    const ushort_t* arow = wt + (size_t)(ocb * 64 + wv * 16 + l16) * Kpad;

    f32x4 acc[4];
#pragma unroll
    for (int cn = 0; cn < 4; ++cn) acc[cn] = (f32x4){0.f, 0.f, 0.f, 0.f};

    __syncthreads();   // offs ready (only barrier in kernel)

    // prefetch step 0
    short8 a0 = ld16(arow + quad * 8);
    int off0 = offs[quad];
    short8 b0[4];
#pragma unroll
    for (int cn = 0; cn < 4; ++cn)
        b0[cn] = A16 ? ld16(inb + bbase[cn] + off0) : ld2x8(inb + bbase[cn] + off0);

    for (int ks = 0; ks < NKS; ++ks) {
        short8 a1; short8 b1[4];
        if (ks + 1 < NKS) {
            const int ko = (ks + 1) * 32 + quad * 8;
            a1 = ld16(arow + ko);
            const int off = offs[(ks + 1) * 4 + quad];
#pragma unroll
            for (int cn = 0; cn < 4; ++cn)
                b1[cn] = A16 ? ld16(inb + bbase[cn] + off) : ld2x8(inb + bbase[cn] + off);
        }
#pragma unroll
        for (int cn = 0; cn < 4; ++cn)
            acc[cn] = __builtin_amdgcn_mfma_f32_16x16x32_bf16(a0, b0[cn], acc[cn], 0, 0, 0);
        a0 = a1;
#pragma unroll
        for (int cn = 0; cn < 4; ++cn) b0[cn] = b1[cn];
    }

    const int oc0 = ocb * 64 + wv * 16 + quad * 4;
    const float bi0 = bias[oc0], bi1 = bias[oc0 + 1], bi2 = bias[oc0 + 2], bi3 = bias[oc0 + 3];
#pragma unroll
    for (int cn = 0; cn < 4; ++cn) {
        int n = n_blk + cn * 16 + l16;
        if (n < HW) {
            int y = n / Wout, x = n - y * Wout;
            size_t base = (((size_t)b * OHp + y + OPAD) * OWp + x + OPAD) * COUT + oc0;
            ushort4 o;
            o.x = f2bf(fmaxf(acc[cn][0] + bi0, 0.f));
            o.y = f2bf(fmaxf(acc[cn][1] + bi1, 0.f));
            o.z = f2bf(fmaxf(acc[cn][2] + bi2, 0.f));
            o.w = f2bf(fmaxf(acc[cn][3] + bi3, 0.f));
            *(ushort4*)&out[base] = o;
        }
    }
}

// ====================================================================
// LDS-free generic bf16 MFMA GEMM: out[oc][n] = sum_k A[oc][k]*B[k][n];
// B[k][n] = Bsrc[row(n)*RS + k]. MODE 0: row=n; MODE 1: row=(1+(n&15))*88+(n>>4).
// ====================================================================
template <int MODE, bool HASBIAS, bool SC1>
__global__ __launch_bounds__(256) void gemm_dmfma(
    const ushort_t* __restrict__ Bsrc, const ushort_t* __restrict__ wt,
    const float* __restrict__ bias, float* __restrict__ out,
    int RS, int N, int NKS, int sn, int sc) {
    const int tid = threadIdx.x;
    const int wv = tid >> 6, lane = tid & 63;
    const int quad = lane >> 4, l16 = lane & 15;
    const int n_blk = blockIdx.x * 64;
    const int ocb = blockIdx.y;
    const int Kpad = NKS * 32;

    int bbase[4];
#pragma unroll
    for (int cn = 0; cn < 4; ++cn) {
        int n = n_blk + cn * 16 + l16;
        if (n >= N) n = N - 1;
        int row = (MODE == 1) ? (1 + (n & 15)) * MM + (n >> 4) : n;
        bbase[cn] = row * RS;
    }
    const ushort_t* arow = wt + (size_t)(ocb * 64 + wv * 16 + l16) * Kpad;

    f32x4 acc[4];
#pragma unroll
    for (int cn = 0; cn < 4; ++cn) acc[cn] = (f32x4){0.f, 0.f, 0.f, 0.f};

    short8 a0 = ld16(arow + quad * 8);
    short8 b0[4];
#pragma unroll
    for (int cn = 0; cn < 4; ++cn) b0[cn] = ld16(Bsrc + bbase[cn] + quad * 8);

    for (int ks = 0; ks < NKS; ++ks) {
        short8 a1; short8 b1[4];
        if (ks + 1 < NKS) {
            const int ko = (ks + 1) * 32 + quad * 8;
            a1 = ld16(arow + ko);
#pragma unroll
            for (int cn = 0; cn < 4; ++cn) b1[cn] = ld16(Bsrc + bbase[cn] + ko);
        }
#pragma unroll
        for (int cn = 0; cn < 4; ++cn)
            acc[cn] = __builtin_amdgcn_mfma_f32_16x16x32_bf16(a0, b0[cn], acc[cn], 0, 0, 0);
        a0 = a1;
#pragma unroll
        for (int cn = 0; cn < 4; ++cn) b0[cn] = b1[cn];
    }

    const int oc0 = ocb * 64 + wv * 16 + quad * 4;
    float bb[4] = {0.f, 0.f, 0.f, 0.f};
    if (HASBIAS) { bb[0] = bias[oc0]; bb[1] = bias[oc0+1]; bb[2] = bias[oc0+2]; bb[3] = bias[oc0+3]; }
#pragma unroll
    for (int cn = 0; cn < 4; ++cn) {
        int n = n_blk + cn * 16 + l16;
        if (n < N) {
            if (SC1) {
                float4 o;
                o.x = acc[cn][0] + bb[0]; o.y = acc[cn][1] + bb[1];
                o.z = acc[cn][2] + bb[2]; o.w = acc[cn][3] + bb[3];
                *(float4*)&out[(size_t)n * sn + oc0] = o;
            } else {
#pragma unroll
                for (int reg = 0; reg < 4; ++reg)
                    out[(size_t)n * sn + (size_t)(oc0 + reg) * sc] = acc[cn][reg] + bb[reg];
            }
        }
    }
}

// ---------- maxpool k3 s2 VALID, NHWC bf16 ----------
__global__ void pool_nhwc(const ushort_t* __restrict__ in, ushort_t* __restrict__ out,
                          int C, int Hin, int Win, int Hout, int Wout,
                          int OHp, int OWp, int OPAD) {
    int total = BATCH * C * Hout * Wout;
    int idx = blockIdx.x * 256 + threadIdx.x;
    if (idx >= total) return;
    int c = idx % C; int r = idx / C;
    int x = r % Wout; r /= Wout;
    int y = r % Hout; int b = r / Hout;
    const int rs = Win * C;
    const ushort_t* p = in + (((size_t)b * Hin + 2 * y) * Win + 2 * x) * C + c;
    float m = b2f(p[0]);
    m = fmaxf(m, b2f(p[C])); m = fmaxf(m, b2f(p[2 * C]));
    m = fmaxf(m, b2f(p[rs])); m = fmaxf(m, b2f(p[rs + C])); m = fmaxf(m, b2f(p[rs + 2 * C]));
    m = fmaxf(m, b2f(p[2 * rs])); m = fmaxf(m, b2f(p[2 * rs + C])); m = fmaxf(m, b2f(p[2 * rs + 2 * C]));
    out[(((size_t)b * OHp + y + OPAD) * OWp + x + OPAD) * C + c] = f2bf(m);
}

// ---------- pool5: NHWC bf16 -> P fp32 [b][m][d] + PB bf16 + XfPad ----------
__global__ void pool5_k(const ushort_t* __restrict__ in, float* __restrict__ P,
                        ushort_t* __restrict__ PB, ushort_t* __restrict__ XfPad) {
    int total = BATCH * 256 * MM;
    int idx = blockIdx.x * 256 + threadIdx.x;
    if (idx >= total) return;
    int c = idx % 256; int r = idx / 256;
    int x = r % W5P; r /= W5P;
    int y = r % H5P; int b = r / H5P;
    const int rs = W2P * 256;
    const ushort_t* p = in + (((size_t)b * H2P + 2 * y) * W2P + 2 * x) * 256 + c;
    float m = b2f(p[0]);
    m = fmaxf(m, b2f(p[256])); m = fmaxf(m, b2f(p[512]));
    m = fmaxf(m, b2f(p[rs])); m = fmaxf(m, b2f(p[rs + 256])); m = fmaxf(m, b2f(p[rs + 512]));
    m = fmaxf(m, b2f(p[2 * rs])); m = fmaxf(m, b2f(p[2 * rs + 256])); m = fmaxf(m, b2f(p[2 * rs + 512]));
    int mm = y * W5P + x;
    size_t o = ((size_t)b * MM + mm) * 256 + c;
    P[o] = m;
    ushort_t mb = f2bf(m);
    PB[o] = mb;
    if (b == 0) XfPad[(size_t)(mm + 1) * 256 + c] = mb;
}

// ---------- v[c] = max_m xc[c*88+m] ----------
__global__ void vmax_k(const float* __restrict__ xc, float* __restrict__ v) {
    int c = blockIdx.x * 64 + threadIdx.x;
    float m = -INFINITY;
    for (int j = 0; j < MM; ++j) m = fmaxf(m, xc[(size_t)c * MM + j]);
    v[c] = m;
}

__global__ void xhat_k(const float* __restrict__ v, const float* __restrict__ wt,
                       const float* __restrict__ bt, float* __restrict__ xhat) {
    __shared__ float lv[256];
    for (int j = threadIdx.x; j < 256; j += 256) lv[j] = v[j];
    __syncthreads();
    int idx = blockIdx.x * 256 + threadIdx.x;
    if (idx >= DD * MM) return;
    int k = idx % MM, o = idx / MM;
    float acc = bt[o];
    for (int i = 0; i < 256; ++i) acc = fmaf(lv[i], wt[(i * 256 + o) * MM + k], acc);
    xhat[idx] = acc;
}

__global__ void s1_k(const float* __restrict__ Y1, float* __restrict__ S1) {
    int idx = blockIdx.x * 256 + threadIdx.x;
    if (idx >= T_EX * 512) return;
    int c = idx % 512, t = idx / 512;
    float acc = 0.f;
    for (int m = 0; m < MM; ++m) acc += Y1[(m * T_EX + t) * 512 + c];
    S1[idx] = acc;
}

__global__ void h1_k(const float* __restrict__ Y1, const float* __restrict__ S1,
                     const float* __restrict__ bs1, ushort_t* __restrict__ h1b) {
    int idx = blockIdx.x * 256 + threadIdx.x;
    if (idx >= TM * 512) return;
    int c = idx % 512; int n = idx / 512;
    int t = n % T_EX;
    float val = S1[t * 512 + c] + bs1[c];
    if (t == 0) val -= Y1[idx];
    h1b[idx] = f2bf(lrelu(val));
}

__global__ void s2_k(const float* __restrict__ Y2, float* __restrict__ S2) {
    int idx = blockIdx.x * 256 + threadIdx.x;
    if (idx >= T_EX * 256) return;
    int c = idx % 256, t = idx / 256;
    float acc = 0.f;
    for (int m = 0; m < MM; ++m) acc += Y2[(m * T_EX + t) * 256 + c];
    S2[idx] = acc;
}

__global__ void h2_k(const float* __restrict__ Y2, const float* __restrict__ S2,
                     const float* __restrict__ bs2, float* __restrict__ h2) {
    int idx = blockIdx.x * 256 + threadIdx.x;
    if (idx >= TM * 256) return;
    int c = idx % 256; int n = idx / 256;
    int t = n % T_EX;
    float val = S2[t * 256 + c] + bs2[c];
    if (t == 0) val -= Y2[idx];
    h2[idx] = lrelu(val);
}

__global__ void v1vx_k(const float* __restrict__ h2, const float* __restrict__ xhat,
                       float* __restrict__ V1, float* __restrict__ Vx) {
    int idx = blockIdx.x * 256 + threadIdx.x;
    if (idx >= DD * MM) return;
    int m = idx % MM, d = idx / MM;
    float mx = -INFINITY;
    for (int t = 0; t < T_EX; ++t) mx = fmaxf(mx, h2[(m * T_EX + t) * 256 + d]);
    V1[idx] = mx;
    Vx[idx] = mx + xhat[idx];
}

__global__ void lin88_k(const float* __restrict__ Wg, const float* __restrict__ bg,
                        const float* __restrict__ Wh, const float* __restrict__ bh,
                        const float* __restrict__ Vin, float* __restrict__ Gout,
                        float* __restrict__ Hout) {
    int idx = blockIdx.x * 256 + threadIdx.x;
    if (idx >= DD * MM) return;
    const float* W = blockIdx.y ? Wh : Wg;
    const float* bias = blockIdx.y ? bh : bg;
    float* out = blockIdx.y ? Hout : Gout;
    int m = idx % MM, o = idx / MM;
    const float* wr = W + o * 256;
    float acc = bias[o];
    for (int i = 0; i < 256; ++i) acc = fmaf(wr[i], Vin[i * MM + m], acc);
    out[idx] = acc;
}

__global__ void smat_k(const float* __restrict__ Hh, const float* __restrict__ G,
                       float* __restrict__ Sm) {
    int idx = blockIdx.x * 256 + threadIdx.x;
    if (idx >= MM * MM) return;
    int i = idx % MM, j = idx / MM;
    float acc = 0.f;
    for (int c = 0; c < 256; ++c) acc = fmaf(Hh[c * MM + j], G[c * MM + i], acc);
    Sm[idx] = acc;
}

__global__ void softmax_k(const float* __restrict__ S, float* __restrict__ A2) {
    int j = blockIdx.x; int i = threadIdx.x;
    __shared__ float red[128];
    float val = (i < MM) ? S[j * MM + i] : -INFINITY;
    red[i] = val; __syncthreads();
    for (int s = 64; s > 0; s >>= 1) {
        if (i < s) red[i] = fmaxf(red[i], red[i + s]);
        __syncthreads();
    }
    float mx = red[0]; __syncthreads();
    float e = (i < MM) ? expf(val - mx) : 0.f;
    red[i] = e; __syncthreads();
    for (int s = 64; s > 0; s >>= 1) {
        if (i < s) red[i] += red[i + s];
        __syncthreads();
    }
    float inv = 1.f / red[0];
    if (i < MM) A2[j * MM + i] = e * inv;
}

__global__ void t1_k(const float* __restrict__ V1, const float* __restrict__ wc1,
                     float* __restrict__ t1) {
    int idx = blockIdx.x * 256 + threadIdx.x;
    if (idx >= MM * 384) return;
    int c = idx % 384, m = idx / 384;
    float acc = 0.f;
    for (int d = 0; d < 256; ++d) acc = fmaf(V1[d * MM + m], wc1[d * 384 + c], acc);
    t1[idx] = acc;
}

__global__ void c1_k(const float* __restrict__ A2, const float* __restrict__ t1,
                     const float* __restrict__ bc1, float* __restrict__ c1) {
    int idx = blockIdx.x * 256 + threadIdx.x;
    if (idx >= MM * 384) return;
    int c = idx % 384, j = idx / 384;
    float acc = bc1[c];
    for (int i = 0; i < MM; ++i) acc = fmaf(A2[j * MM + i], t1[i * 384 + c], acc);
    c1[idx] = lrelu(acc);
}

__global__ void t2_k(const float* __restrict__ c1, const float* __restrict__ wc2,
                     float* __restrict__ t2) {
    int idx = blockIdx.x * 256 + threadIdx.x;
    if (idx >= MM * 256) return;
    int c = idx % 256, m = idx / 256;
    const float* cr = c1 + m * 384;
    float acc = 0.f;
    for (int d = 0; d < 384; ++d) acc = fmaf(cr[d], wc2[d * 256 + c], acc);
    t2[idx] = acc;
}

__global__ void v2_k(const float* __restrict__ A2, const float* __restrict__ t2,
                     const float* __restrict__ bc2, float* __restrict__ V2m) {
    int idx = blockIdx.x * 256 + threadIdx.x;
    if (idx >= MM * 256) return;
    int c = idx % 256, j = idx / 256;
    float acc = bc2[c];
    for (int i = 0; i < MM; ++i) acc = fmaf(A2[j * MM + i], t2[i * 256 + c], acc);
    V2m[idx] = lrelu(acc);
}

__global__ void final_k(const float* __restrict__ Xf2, const float* __restrict__ V2m,
                        float* __restrict__ out) {
    __shared__ float red[256];
    float acc = 0.f;
    for (int idx = threadIdx.x; idx < DD * MM; idx += 256)
        acc = fmaf(Xf2[idx], V2m[idx], acc);
    red[threadIdx.x] = acc; __syncthreads();
    for (int s = 128; s > 0; s >>= 1) {
        if (threadIdx.x < s) red[threadIdx.x] += red[threadIdx.x + s];
        __syncthreads();
    }
    if (threadIdx.x == 0) out[0] = red[0];
}

extern "C" void kernel_launch(void* const* d_in, const int* in_sizes, int n_in,
                              void* d_out, int out_size, void* d_ws, size_t ws_size,
                              hipStream_t stream) {
    const float* search = (const float*)d_in[0];
    const float* exemp  = (const float*)d_in[1];
    const float* aw1 = (const float*)d_in[2];  const float* ab1 = (const float*)d_in[3];
    const float* aw2 = (const float*)d_in[4];  const float* ab2 = (const float*)d_in[5];
    const float* aw3 = (const float*)d_in[6];  const float* ab3 = (const float*)d_in[7];
    const float* aw4 = (const float*)d_in[8];  const float* ab4 = (const float*)d_in[9];
    const float* aw5 = (const float*)d_in[10]; const float* ab5 = (const float*)d_in[11];
    const float* wcd = (const float*)d_in[12]; const float* bcd = (const float*)d_in[13];
    const float* wt  = (const float*)d_in[14]; const float* bt  = (const float*)d_in[15];
    const float* ws1 = (const float*)d_in[16]; const float* bs1 = (const float*)d_in[17];
    const float* ws2 = (const float*)d_in[18]; const float* bs2 = (const float*)d_in[19];
    const float* wg  = (const float*)d_in[20]; const float* bg  = (const float*)d_in[21];
    const float* wh  = (const float*)d_in[22]; const float* bh  = (const float*)d_in[23];
    const float* wc1 = (const float*)d_in[24]; const float* bc1 = (const float*)d_in[25];
    const float* wc2 = (const float*)d_in[26]; const float* bc2 = (const float*)d_in[27];

    float* ws = (float*)d_ws;
    float* R1 = ws;
    float* R2 = ws + 3870720;
    float* R3 = ws + 7544832;
    float* Wg = ws + 8628864;

    ushort_t* in1p  = (ushort_t*)R1;
    ushort_t* c1out = (ushort_t*)R2;
    ushort_t* p1out = (ushort_t*)R3;
    ushort_t* c2out = (ushort_t*)R1;
    ushort_t* p2out = (ushort_t*)R2;
    ushort_t* c3out = (ushort_t*)(R2 + 775200);
    ushort_t* c4out = (ushort_t*)R1;
    ushort_t* c5out = (ushort_t*)R3;
    ushort_t* WT    = (ushort_t*)Wg;

    // ---- conv stack (row-major weight layout, Kpad8 = NKS*4) ----
    zfill_k<<<(965500 + 255) / 256, 256, 0, stream>>>((float4*)R1, 965500);
    prep1_k<<<(BATCH * H0 * W0 + 255) / 256, 256, 0, stream>>>(search, exemp, in1p);
    wprep_k<<<(4352 + 255) / 256, 256, 0, stream>>>(aw1, WT, 11, 12, 11, 4, 3, 68, 4352);
    conv_dmfma<4, false><<<dim3(106, 1, BATCH), 256, 0, stream>>>(
        in1p, WT, ab1, c1out, HP1, WP1, 4, W1, H1 * W1, 17, 12, H1, W1, 0, 64);
    zfill_k<<<(270504 + 255) / 256, 256, 0, stream>>>((float4*)R3, 270504);
    pool_nhwc<<<(BATCH * 64 * H1P * W1P + 255) / 256, 256, 0, stream>>>(
        c1out, p1out, 64, H1, W1, H1P, W1P, 51, 39, 2);
    wprep_k<<<(38400 + 255) / 256, 256, 0, stream>>>(aw2, WT, 5, 5, 5, 64, 64, 200, 38400);
    conv_dmfma<1, true><<<dim3(26, 3, BATCH), 256, 0, stream>>>(
        p1out, WT, ab2, c2out, 51, 39, 64, W1P, H1P * W1P, 50, 5, H1P, W1P, 0, 192);
    zfill_k<<<(581400 + 255) / 256, 256, 0, stream>>>((float4*)R2, 581400);
    pool_nhwc<<<(BATCH * 192 * H2P * W2P + 255) / 256, 256, 0, stream>>>(
        c2out, p2out, 192, H1P, W1P, H2P, W2P, 25, 19, 1);
    wprep_k<<<(82944 + 255) / 256, 256, 0, stream>>>(aw3, WT, 3, 3, 3, 192, 192, 216, 82944);
    conv_dmfma<1, true><<<dim3(7, 6, BATCH), 256, 0, stream>>>(
        p2out, WT, ab3, c3out, 25, 19, 192, W2P, H2P * W2P, 54, 3, 25, 19, 1, 384);
    zfill_k<<<(258400 + 255) / 256, 256, 0, stream>>>((float4*)R1, 258400);
    wprep_k<<<(110592 + 255) / 256, 256, 0, stream>>>(aw4, WT, 3, 3, 3, 384, 384, 432, 110592);
    conv_dmfma<1, true><<<dim3(7, 4, BATCH), 256, 0, stream>>>(
        c3out, WT, ab4, c4out, 25, 19, 384, W2P, H2P * W2P, 108, 3, 25, 19, 1, 256);
    wprep_k<<<(73728 + 255) / 256, 256, 0, stream>>>(aw5, WT, 3, 3, 3, 256, 256, 288, 73728);
    conv_dmfma<1, true><<<dim3(7, 4, BATCH), 256, 0, stream>>>(
        c4out, WT, ab5, c5out, 25, 19, 256, W2P, H2P * W2P, 72, 3, H2P, W2P, 0, 256);

    // ---- tail region layout in R1 ----
    float*    P      = R1 + 2417664;
    ushort_t* PB     = (ushort_t*)(R1 + 2800640);
    ushort_t* XfPad  = (ushort_t*)(R1 + 2992128);
    float*    xc     = R1 + 3003648;

    ushort_t* WS1T = (ushort_t*)Wg;
    ushort_t* WS2T = (ushort_t*)(Wg + 65536);
    ushort_t* WCDT = (ushort_t*)(Wg + 131072);
    wprep2_k<0><<<(16384 + 255) / 256, 256, 0, stream>>>(ws1, WS1T, 1, 512, 32, 16384);
    wprep2_k<0><<<(16384 + 255) / 256, 256, 0, stream>>>(ws2, WS2T, 1, 256, 64, 16384);
    wprep2_k<1><<<(24576 + 255) / 256, 256, 0, stream>>>(wcd, WCDT, 0, 0, 96, 24576);

    zfill_k<<<(2880 + 255) / 256, 256, 0, stream>>>((float4*)XfPad, 2880);
    pool5_k<<<(BATCH * 256 * MM + 255) / 256, 256, 0, stream>>>(c5out, P, PB, XfPad);
    float* Xf2 = P;

    float* v_   = R1 + 0;
    float* xhat = R1 + 1024;
    float* Y1   = R1 + 23552;
    float* S1   = R1 + 744448;
    ushort_t* h1b = (ushort_t*)(R1 + 752640);
    float* Y2   = R1 + 1473536;
    float* S2   = R1 + 1833984;
    float* h2   = R1 + 1838080;
    float* V1   = R1 + 2198528;
    float* Vx   = R1 + 2221056;
    float* G    = R1 + 2243584;
    float* Hh   = R1 + 2266112;
    float* Sm   = R1 + 2288640;
    float* A2   = R1 + 2296832;
    float* t1   = R1 + 2305024;
    float* c1   = R1 + 2338816;
    float* t2   = R1 + 2372608;
    float* V2m  = R1 + 2395136;

    gemm_dmfma<0, true, false><<<dim3(2, 4), 256, 0, stream>>>(
        XfPad, WCDT, bcd, xc, 256, MM, 24, 1, MM);
    vmax_k<<<4, 64, 0, stream>>>(xc, v_);
    xhat_k<<<(DD * MM + 255) / 256, 256, 0, stream>>>(v_, wt, bt, xhat);

    gemm_dmfma<1, false, true><<<dim3(22, 8), 256, 0, stream>>>(
        PB, WS1T, nullptr, Y1, 256, TM, 8, 512, 1);
    s1_k<<<(T_EX * 512 + 255) / 256, 256, 0, stream>>>(Y1, S1);
    h1_k<<<(TM * 512 + 255) / 256, 256, 0, stream>>>(Y1, S1, bs1, h1b);
    gemm_dmfma<0, false, true><<<dim3(22, 4), 256, 0, stream>>>(
        h1b, WS2T, nullptr, Y2, 512, TM, 16, 256, 1);
    s2_k<<<(T_EX * 256 + 255) / 256, 256, 0, stream>>>(Y2, S2);
    h2_k<<<(TM * 256 + 255) / 256, 256, 0, stream>>>(Y2, S2, bs2, h2);
    v1vx_k<<<(DD * MM + 255) / 256, 256, 0, stream>>>(h2, xhat, V1, Vx);

    lin88_k<<<dim3((DD * MM + 255) / 256, 2), 256, 0, stream>>>(wg, bg, wh, bh, Vx, G, Hh);
    smat_k<<<(MM * MM + 255) / 256, 256, 0, stream>>>(Hh, G, Sm);
    softmax_k<<<MM, 128, 0, stream>>>(Sm, A2);

    t1_k<<<(MM * 384 + 255) / 256, 256, 0, stream>>>(V1, wc1, t1);
    c1_k<<<(MM * 384 + 255) / 256, 256, 0, stream>>>(A2, t1, bc1, c1);
    t2_k<<<(MM * 256 + 255) / 256, 256, 0, stream>>>(c1, wc2, t2);
    v2_k<<<(MM * 256 + 255) / 256, 256, 0, stream>>>(A2, t2, bc2, V2m);

    final_k<<<1, 256, 0, stream>>>(Xf2, V2m, (float*)d_out);
}

// Round 8
// 603.371 us; speedup vs baseline: 1.4910x; 1.4910x over previous
//
#include <hip/hip_runtime.h>
#include <hip/hip_bf16.h>
#include <math.h>

// ---------- dims ----------
#define BATCH 17
#define T_EX 16
#define H0 383
#define W0 287
#define C1 64
#define H1 95
#define W1 71
#define H1P 47
#define W1P 35
#define C2 192
#define H2P 23
#define W2P 17
#define C3 384
#define C45 256
#define H5P 11
#define W5P 8
#define DD 256
#define MM 88
#define TM 1408

#define HP1 389
#define WP1 292

typedef unsigned short ushort_t;
typedef __attribute__((ext_vector_type(8))) short short8;
typedef __attribute__((ext_vector_type(4))) float f32x4;

__device__ __forceinline__ float lrelu(float v) { return v > 0.f ? v : 0.01f * v; }

__device__ __forceinline__ ushort_t f2bf(float f) {
    unsigned int u = __float_as_uint(f);
    unsigned int r = (u + 0x7fffu + ((u >> 16) & 1u)) >> 16;
    return (ushort_t)r;
}
__device__ __forceinline__ float b2f(ushort_t b) {
    return __uint_as_float(((unsigned int)b) << 16);
}
__device__ __forceinline__ short8 ld16(const ushort_t* p) { return *(const short8*)p; }
__device__ __forceinline__ short8 ld2x8(const ushort_t* p) {
    union { uint2 u[2]; short8 s; } uu;
    uu.u[0] = *(const uint2*)p;
    uu.u[1] = *(const uint2*)(p + 4);
    return uu.s;
}

// ---------- zero fill ----------
__global__ void zfill_k(float4* __restrict__ p, int n4) {
    int idx = blockIdx.x * 256 + threadIdx.x;
    if (idx < n4) p[idx] = (float4){0.f, 0.f, 0.f, 0.f};
}

// ---------- conv1 input prep: fp32 NCHW -> bf16 NHWC padded (C=4, pad 2) ----------
__global__ void prep1_k(const float* __restrict__ search, const float* __restrict__ exemp,
                        ushort_t* __restrict__ out) {
    int idx = blockIdx.x * 256 + threadIdx.x;
    if (idx >= BATCH * H0 * W0) return;
    int ix = idx % W0; int t = idx / W0;
    int iy = t % H0; int b = t / H0;
    const float* src = (b == 0) ? search : exemp + (size_t)(b - 1) * 3 * H0 * W0;
    const int hw = H0 * W0;
    float v0 = src[iy * W0 + ix];
    float v1 = src[hw + iy * W0 + ix];
    float v2 = src[2 * hw + iy * W0 + ix];
    ushort4 o;
    o.x = f2bf(v0); o.y = f2bf(v1); o.z = f2bf(v2); o.w = 0;
    *(ushort4*)&out[(((size_t)b * HP1 + iy + 2) * WP1 + ix + 2) * 4] = o;
}

// ---------- conv weight prep: OIHW fp32 -> bf16 MFMA tiles, K-order (ky,kx,ic) ----------
// tile chunk idx = ((ocb*NKS + ks)*256 + k8*64 + m), holds w[ocb*64+m][ks*32+k8*8+j]
__global__ void wprep_k(const float* __restrict__ w, ushort_t* __restrict__ out,
                        int KH, int KWl, int KWr, int CINl, int CINr,
                        int NKS, int nch) {
    int idx = blockIdx.x * 256 + threadIdx.x;
    if (idx >= nch) return;
    int c = idx & 255;
    int rest = idx >> 8;
    int ks = rest % NKS;
    int ocb = rest / NKS;
    int k8 = c >> 6, m = c & 63;
    int oc = ocb * 64 + m;
    int KWC = KWl * CINl;
    ushort_t* o = out + (size_t)idx * 8;
#pragma unroll
    for (int j = 0; j < 8; ++j) {
        int kg = ks * 32 + k8 * 8 + j;
        int ky = kg / KWC; int rem = kg - ky * KWC;
        int kx = rem / CINl; int ic = rem - kx * CINl;
        float v = 0.f;
        if (ky < KH && kx < KWr && ic < CINr)
            v = w[(((size_t)oc * CINr + ic) * KH + ky) * KWr + kx];
        o[j] = f2bf(v);
    }
}

// ---------- fused gemm weight prep (ws1 | ws2 | wcd), tiled layout ----------
__global__ void wprep_gemm_k(const float* __restrict__ ws1, const float* __restrict__ ws2,
                             const float* __restrict__ wcd, ushort_t* __restrict__ WS1T,
                             ushort_t* __restrict__ WS2T, ushort_t* __restrict__ WCDT) {
    int idx = blockIdx.x * 256 + threadIdx.x;
    const float* src; ushort_t* dst; int NKS, mode = 0, sa = 1, sk = 0, base;
    if (idx < 16384)       { src = ws1; dst = WS1T; NKS = 8;  sk = 512; base = idx; }
    else if (idx < 32768)  { src = ws2; dst = WS2T; NKS = 16; sk = 256; base = idx - 16384; }
    else if (idx < 57344)  { src = wcd; dst = WCDT; NKS = 24; mode = 1; base = idx - 32768; }
    else return;
    int c = base & 255;
    int rest = base >> 8;
    int ks = rest % NKS;
    int ocb = rest / NKS;
    int k8 = c >> 6, m = c & 63;
    int oc = ocb * 64 + m;
    ushort_t* o = dst + (size_t)base * 8;
#pragma unroll
    for (int j = 0; j < 8; ++j) {
        int kg = ks * 32 + k8 * 8 + j;
        float v;
        if (mode == 0) v = src[(size_t)oc * sa + (size_t)kg * sk];
        else           v = src[(size_t)oc * 768 + (kg & 255) * 3 + (kg >> 8)];
        o[j] = f2bf(v);
    }
}

// ====================================================================
// bf16 MFMA implicit-GEMM conv: A fragments DIRECT from global (tiled
// layout -> 256B-contiguous per quad-group, L2-resident); B staged in
// double-buffered LDS (coalesced-ish gather), one barrier per step.
// ====================================================================
template <int STRIDE, bool A16>
__global__ __launch_bounds__(256) void conv_mfma3(
    const ushort_t* __restrict__ inp, const ushort_t* __restrict__ wt,
    const float* __restrict__ bias, ushort_t* __restrict__ out,
    int Hp, int Wp, int C, int Wout, int HW, int NKS, int KWl,
    int OHp, int OWp, int OPAD, int COUT) {
    const int tid = threadIdx.x;
    const int wv = tid >> 6, lane = tid & 63;
    const int quad = lane >> 4, l16 = lane & 15;
    const int n_blk = blockIdx.x * 64;
    const int ocb = blockIdx.y;
    const int b = blockIdx.z;

    __shared__ ushort_t Bs[2][2048];
    __shared__ int offs[448];

    const int KWC = KWl * C;
    for (int g = tid; g < NKS * 4; g += 256) {
        int kg = g * 8;
        int ky = kg / KWC; int rem = kg - ky * KWC;
        int kx = rem / C; int c8 = rem - kx * C;
        offs[g] = (ky * Wp + kx) * C + c8;
    }

    const ushort_t* inb = inp + (size_t)b * Hp * Wp * C;
    int n_g = n_blk + lane;
    int n_gc = n_g < HW ? n_g : HW - 1;
    int oy = n_gc / Wout, ox = n_gc - oy * Wout;
    const int base0 = (oy * STRIDE * Wp + ox * STRIDE) * C;

    f32x4 acc[4];
#pragma unroll
    for (int cn = 0; cn < 4; ++cn) acc[cn] = (f32x4){0.f, 0.f, 0.f, 0.f};

    const ushort_t* wblk = wt + (size_t)ocb * NKS * 2048;
    const int afrag = (quad * 64 + wv * 16 + l16) * 8;

    __syncthreads();   // offs ready

    // prologue: A frag 0 (global) + B stage 0
    short8 a0 = ld16(wblk + afrag);
    {
        const ushort_t* src = inb + base0 + offs[wv];
        short8 bval = A16 ? ld16(src) : ld2x8(src);
        *(short8*)&Bs[0][tid * 8] = bval;
    }
    __syncthreads();

    for (int ks = 0; ks < NKS; ++ks) {
        const int cur = ks & 1, nxt = cur ^ 1;
        short8 a1, bn;
        const bool more = (ks + 1 < NKS);
        if (more) {
            a1 = ld16(wblk + (ks + 1) * 2048 + afrag);
            const ushort_t* src = inb + base0 + offs[(ks + 1) * 4 + wv];
            bn = A16 ? ld16(src) : ld2x8(src);
        }
#pragma unroll
        for (int cn = 0; cn < 4; ++cn) {
            const short8 bfr = *(const short8*)&Bs[cur][(quad * 64 + cn * 16 + l16) * 8];
            acc[cn] = __builtin_amdgcn_mfma_f32_16x16x32_bf16(a0, bfr, acc[cn], 0, 0, 0);
        }
        if (more) *(short8*)&Bs[nxt][tid * 8] = bn;
        a0 = a1;
        __syncthreads();
    }

    const int oc0 = ocb * 64 + wv * 16 + quad * 4;
    const float bi0 = bias[oc0], bi1 = bias[oc0 + 1], bi2 = bias[oc0 + 2], bi3 = bias[oc0 + 3];
#pragma unroll
    for (int cn = 0; cn < 4; ++cn) {
        int n = n_blk + cn * 16 + l16;
        if (n < HW) {
            int y = n / Wout, x = n - y * Wout;
            size_t base = (((size_t)b * OHp + y + OPAD) * OWp + x + OPAD) * COUT + oc0;
            ushort4 o;
            o.x = f2bf(fmaxf(acc[cn][0] + bi0, 0.f));
            o.y = f2bf(fmaxf(acc[cn][1] + bi1, 0.f));
            o.z = f2bf(fmaxf(acc[cn][2] + bi2, 0.f));
            o.w = f2bf(fmaxf(acc[cn][3] + bi3, 0.f));
            *(ushort4*)&out[base] = o;
        }
    }
}

// ====================================================================
// Generic bf16 MFMA GEMM: A direct from global (tiled), B LDS dbuf.
// out[oc][n] = sum_k A[oc][k]*B[k][n]; B[k][n] = Bsrc[row(n)*RS + k].
// MODE 0: row=n; MODE 1: row=(1+(n&15))*88+(n>>4).
// ====================================================================
template <int MODE, bool HASBIAS, bool SC1>
__global__ __launch_bounds__(256) void gemm_mfma3(
    const ushort_t* __restrict__ Bsrc, const ushort_t* __restrict__ wt,
    const float* __restrict__ bias, float* __restrict__ out,
    int RS, int N, int NKS, int sn, int sc) {
    const int tid = threadIdx.x;
    const int wv = tid >> 6, lane = tid & 63;
    const int quad = lane >> 4, l16 = lane & 15;
    const int n_blk = blockIdx.x * 64;
    const int ocb = blockIdx.y;

    __shared__ ushort_t Bs[2][2048];

    int n_g = n_blk + lane;
    int n_gc = n_g < N ? n_g : N - 1;
    int row = (MODE == 1) ? (1 + (n_gc & 15)) * MM + (n_gc >> 4) : n_gc;
    const size_t base0 = (size_t)row * RS;

    f32x4 acc[4];
#pragma unroll
    for (int cn = 0; cn < 4; ++cn) acc[cn] = (f32x4){0.f, 0.f, 0.f, 0.f};

    const ushort_t* wblk = wt + (size_t)ocb * NKS * 2048;
    const int afrag = (quad * 64 + wv * 16 + l16) * 8;

    short8 a0 = ld16(wblk + afrag);
    *(short8*)&Bs[0][tid * 8] = ld16(Bsrc + base0 + wv * 8);
    __syncthreads();

    for (int ks = 0; ks < NKS; ++ks) {
        const int cur = ks & 1, nxt = cur ^ 1;
        short8 a1, bn;
        const bool more = (ks + 1 < NKS);
        if (more) {
            a1 = ld16(wblk + (ks + 1) * 2048 + afrag);
            bn = ld16(Bsrc + base0 + (ks + 1) * 32 + wv * 8);
        }
#pragma unroll
        for (int cn = 0; cn < 4; ++cn) {
            const short8 bfr = *(const short8*)&Bs[cur][(quad * 64 + cn * 16 + l16) * 8];
            acc[cn] = __builtin_amdgcn_mfma_f32_16x16x32_bf16(a0, bfr, acc[cn], 0, 0, 0);
        }
        if (more) *(short8*)&Bs[nxt][tid * 8] = bn;
        a0 = a1;
        __syncthreads();
    }

    const int oc0 = ocb * 64 + wv * 16 + quad * 4;
    float bb[4] = {0.f, 0.f, 0.f, 0.f};
    if (HASBIAS) { bb[0] = bias[oc0]; bb[1] = bias[oc0+1]; bb[2] = bias[oc0+2]; bb[3] = bias[oc0+3]; }
#pragma unroll
    for (int cn = 0; cn < 4; ++cn) {
        int n = n_blk + cn * 16 + l16;
        if (n < N) {
            if (SC1) {
                float4 o;
                o.x = acc[cn][0] + bb[0]; o.y = acc[cn][1] + bb[1];
                o.z = acc[cn][2] + bb[2]; o.w = acc[cn][3] + bb[3];
                *(float4*)&out[(size_t)n * sn + oc0] = o;
            } else {
#pragma unroll
                for (int reg = 0; reg < 4; ++reg)
                    out[(size_t)n * sn + (size_t)(oc0 + reg) * sc] = acc[cn][reg] + bb[reg];
            }
        }
    }
}

// ---------- maxpool k3 s2 VALID, NHWC bf16 ----------
__global__ void pool_nhwc(const ushort_t* __restrict__ in, ushort_t* __restrict__ out,
                          int C, int Hin, int Win, int Hout, int Wout,
                          int OHp, int OWp, int OPAD) {
    int total = BATCH * C * Hout * Wout;
    int idx = blockIdx.x * 256 + threadIdx.x;
    if (idx >= total) return;
    int c = idx % C; int r = idx / C;
    int x = r % Wout; r /= Wout;
    int y = r % Hout; int b = r / Hout;
    const int rs = Win * C;
    const ushort_t* p = in + (((size_t)b * Hin + 2 * y) * Win + 2 * x) * C + c;
    float m = b2f(p[0]);
    m = fmaxf(m, b2f(p[C])); m = fmaxf(m, b2f(p[2 * C]));
    m = fmaxf(m, b2f(p[rs])); m = fmaxf(m, b2f(p[rs + C])); m = fmaxf(m, b2f(p[rs + 2 * C]));
    m = fmaxf(m, b2f(p[2 * rs])); m = fmaxf(m, b2f(p[2 * rs + C])); m = fmaxf(m, b2f(p[2 * rs + 2 * C]));
    out[(((size_t)b * OHp + y + OPAD) * OWp + x + OPAD) * C + c] = f2bf(m);
}

// ---------- pool5: NHWC bf16 -> P fp32 [b][m][d] + PB bf16 + XfPad ----------
__global__ void pool5_k(const ushort_t* __restrict__ in, float* __restrict__ P,
                        ushort_t* __restrict__ PB, ushort_t* __restrict__ XfPad) {
    int total = BATCH * 256 * MM;
    int idx = blockIdx.x * 256 + threadIdx.x;
    if (idx >= total) return;
    int c = idx % 256; int r = idx / 256;
    int x = r % W5P; r /= W5P;
    int y = r % H5P; int b = r / H5P;
    const int rs = W2P * 256;
    const ushort_t* p = in + (((size_t)b * H2P + 2 * y) * W2P + 2 * x) * 256 + c;
    float m = b2f(p[0]);
    m = fmaxf(m, b2f(p[256])); m = fmaxf(m, b2f(p[512]));
    m = fmaxf(m, b2f(p[rs])); m = fmaxf(m, b2f(p[rs + 256])); m = fmaxf(m, b2f(p[rs + 512]));
    m = fmaxf(m, b2f(p[2 * rs])); m = fmaxf(m, b2f(p[2 * rs + 256])); m = fmaxf(m, b2f(p[2 * rs + 512]));
    int mm = y * W5P + x;
    size_t o = ((size_t)b * MM + mm) * 256 + c;
    P[o] = m;
    ushort_t mb = f2bf(m);
    PB[o] = mb;
    if (b == 0) XfPad[(size_t)(mm + 1) * 256 + c] = mb;
}

// ---------- v[c] = max_m xc[c*88+m] ----------
__global__ void vmax_k(const float* __restrict__ xc, float* __restrict__ v) {
    int c = blockIdx.x * 64 + threadIdx.x;
    float m = -INFINITY;
    for (int j = 0; j < MM; ++j) m = fmaxf(m, xc[(size_t)c * MM + j]);
    v[c] = m;
}

__global__ void xhat_k(const float* __restrict__ v, const float* __restrict__ wt,
                       const float* __restrict__ bt, float* __restrict__ xhat) {
    __shared__ float lv[256];
    for (int j = threadIdx.x; j < 256; j += 256) lv[j] = v[j];
    __syncthreads();
    int idx = blockIdx.x * 256 + threadIdx.x;
    if (idx >= DD * MM) return;
    int k = idx % MM, o = idx / MM;
    float acc = bt[o];
    for (int i = 0; i < 256; ++i) acc = fmaf(lv[i], wt[(i * 256 + o) * MM + k], acc);
    xhat[idx] = acc;
}

__global__ void s1_k(const float* __restrict__ Y1, float* __restrict__ S1) {
    int idx = blockIdx.x * 256 + threadIdx.x;
    if (idx >= T_EX * 512) return;
    int c = idx % 512, t = idx / 512;
    float acc = 0.f;
    for (int m = 0; m < MM; ++m) acc += Y1[(m * T_EX + t) * 512 + c];
    S1[idx] = acc;
}

__global__ void h1_k(const float* __restrict__ Y1, const float* __restrict__ S1,
                     const float* __restrict__ bs1, ushort_t* __restrict__ h1b) {
    int idx = blockIdx.x * 256 + threadIdx.x;
    if (idx >= TM * 512) return;
    int c = idx % 512; int n = idx / 512;
    int t = n % T_EX;
    float val = S1[t * 512 + c] + bs1[c];
    if (t == 0) val -= Y1[idx];
    h1b[idx] = f2bf(lrelu(val));
}

__global__ void s2_k(const float* __restrict__ Y2, float* __restrict__ S2) {
    int idx = blockIdx.x * 256 + threadIdx.x;
    if (idx >= T_EX * 256) return;
    int c = idx % 256, t = idx / 256;
    float acc = 0.f;
    for (int m = 0; m < MM; ++m) acc += Y2[(m * T_EX + t) * 256 + c];
    S2[idx] = acc;
}

__global__ void h2_k(const float* __restrict__ Y2, const float* __restrict__ S2,
                     const float* __restrict__ bs2, float* __restrict__ h2) {
    int idx = blockIdx.x * 256 + threadIdx.x;
    if (idx >= TM * 256) return;
    int c = idx % 256; int n = idx / 256;
    int t = n % T_EX;
    float val = S2[t * 256 + c] + bs2[c];
    if (t == 0) val -= Y2[idx];
    h2[idx] = lrelu(val);
}

__global__ void v1vx_k(const float* __restrict__ h2, const float* __restrict__ xhat,
                       float* __restrict__ V1, float* __restrict__ Vx) {
    int idx = blockIdx.x * 256 + threadIdx.x;
    if (idx >= DD * MM) return;
    int m = idx % MM, d = idx / MM;
    float mx = -INFINITY;
    for (int t = 0; t < T_EX; ++t) mx = fmaxf(mx, h2[(m * T_EX + t) * 256 + d]);
    V1[idx] = mx;
    Vx[idx] = mx + xhat[idx];
}

__global__ void lin88_k(const float* __restrict__ Wg, const float* __restrict__ bg,
                        const float* __restrict__ Wh, const float* __restrict__ bh,
                        const float* __restrict__ Vin, float* __restrict__ Gout,
                        float* __restrict__ Hout) {
    int idx = blockIdx.x * 256 + threadIdx.x;
    if (idx >= DD * MM) return;
    const float* W = blockIdx.y ? Wh : Wg;
    const float* bias = blockIdx.y ? bh : bg;
    float* out = blockIdx.y ? Hout : Gout;
    int m = idx % MM, o = idx / MM;
    const float* wr = W + o * 256;
    float acc = bias[o];
    for (int i = 0; i < 256; ++i) acc = fmaf(wr[i], Vin[i * MM + m], acc);
    out[idx] = acc;
}

// ---------- fused Smat row + softmax: A2[j][:] = softmax_i(Hh[:,j].G[:,i]) ----------
__global__ void smsm_k(const float* __restrict__ Hh, const float* __restrict__ G,
                       float* __restrict__ A2) {
    int j = blockIdx.x;
    int tid = threadIdx.x;   // 128
    __shared__ float row[96];
    __shared__ float red[128];
    for (int i = tid; i < MM; i += 128) {
        float acc = 0.f;
        for (int c = 0; c < 256; ++c) acc = fmaf(Hh[c * MM + j], G[c * MM + i], acc);
        row[i] = acc;
    }
    __syncthreads();
    float val = (tid < MM) ? row[tid] : -INFINITY;
    red[tid] = val; __syncthreads();
    for (int s = 64; s > 0; s >>= 1) {
        if (tid < s) red[tid] = fmaxf(red[tid], red[tid + s]);
        __syncthreads();
    }
    float mx = red[0]; __syncthreads();
    float e = (tid < MM) ? expf(val - mx) : 0.f;
    red[tid] = e; __syncthreads();
    for (int s = 64; s > 0; s >>= 1) {
        if (tid < s) red[tid] += red[tid + s];
        __syncthreads();
    }
    float inv = 1.f / red[0];
    if (tid < MM) A2[j * MM + tid] = e * inv;
}

__global__ void t1_k(const float* __restrict__ V1, const float* __restrict__ wc1,
                     float* __restrict__ t1) {
    int idx = blockIdx.x * 256 + threadIdx.x;
    if (idx >= MM * 384) return;
    int c = idx % 384, m = idx / 384;
    float acc = 0.f;
    for (int d = 0; d < 256; ++d) acc = fmaf(V1[d * MM + m], wc1[d * 384 + c], acc);
    t1[idx] = acc;
}

__global__ void c1_k(const float* __restrict__ A2, const float* __restrict__ t1,
                     const float* __restrict__ bc1, float* __restrict__ c1) {
    int idx = blockIdx.x * 256 + threadIdx.x;
    if (idx >= MM * 384) return;
    int c = idx % 384, j = idx / 384;
    float acc = bc1[c];
    for (int i = 0; i < MM; ++i) acc = fmaf(A2[j * MM + i], t1[i * 384 + c], acc);
    c1[idx] = lrelu(acc);
}

__global__ void t2_k(const float* __restrict__ c1, const float* __restrict__ wc2,
                     float* __restrict__ t2) {
    int idx = blockIdx.x * 256 + threadIdx.x;
    if (idx >= MM * 256) return;
    int c = idx % 256, m = idx / 256;
    const float* cr = c1 + m * 384;
    float acc = 0.f;
    for (int d = 0; d < 384; ++d) acc = fmaf(cr[d], wc2[d * 256 + c], acc);
    t2[idx] = acc;
}

__global__ void v2_k(const float* __restrict__ A2, const float* __restrict__ t2,
                     const float* __restrict__ bc2, float* __restrict__ V2m) {
    int idx = blockIdx.x * 256 + threadIdx.x;
    if (idx >= MM * 256) return;
    int c = idx % 256, j = idx / 256;
    float acc = bc2[c];
    for (int i = 0; i < MM; ++i) acc = fmaf(A2[j * MM + i], t2[i * 256 + c], acc);
    V2m[idx] = lrelu(acc);
}

__global__ void final_k(const float* __restrict__ Xf2, const float* __restrict__ V2m,
                        float* __restrict__ out) {
    __shared__ float red[256];
    float acc = 0.f;
    for (int idx = threadIdx.x; idx < DD * MM; idx += 256)
        acc = fmaf(Xf2[idx], V2m[idx], acc);
    red[threadIdx.x] = acc; __syncthreads();
    for (int s = 128; s > 0; s >>= 1) {
        if (threadIdx.x < s) red[threadIdx.x] += red[threadIdx.x + s];
        __syncthreads();
    }
    if (threadIdx.x == 0) out[0] = red[0];
}

extern "C" void kernel_launch(void* const* d_in, const int* in_sizes, int n_in,
                              void* d_out, int out_size, void* d_ws, size_t ws_size,
                              hipStream_t stream) {
    const float* search = (const float*)d_in[0];
    const float* exemp  = (const float*)d_in[1];
    const float* aw1 = (const float*)d_in[2];  const float* ab1 = (const float*)d_in[3];
    const float* aw2 = (const float*)d_in[4];  const float* ab2 = (const float*)d_in[5];
    const float* aw3 = (const float*)d_in[6];  const float* ab3 = (const float*)d_in[7];
    const float* aw4 = (const float*)d_in[8];  const float* ab4 = (const float*)d_in[9];
    const float* aw5 = (const float*)d_in[10]; const float* ab5 = (const float*)d_in[11];
    const float* wcd = (const float*)d_in[12]; const float* bcd = (const float*)d_in[13];
    const float* wt  = (const float*)d_in[14]; const float* bt  = (const float*)d_in[15];
    const float* ws1 = (const float*)d_in[16]; const float* bs1 = (const float*)d_in[17];
    const float* ws2 = (const float*)d_in[18]; const float* bs2 = (const float*)d_in[19];
    const float* wg  = (const float*)d_in[20]; const float* bg  = (const float*)d_in[21];
    const float* wh  = (const float*)d_in[22]; const float* bh  = (const float*)d_in[23];
    const float* wc1 = (const float*)d_in[24]; const float* bc1 = (const float*)d_in[25];
    const float* wc2 = (const float*)d_in[26]; const float* bc2 = (const float*)d_in[27];

    float* ws = (float*)d_ws;
    float* R1 = ws;
    float* R2 = ws + 3870720;
    float* R3 = ws + 7544832;
    float* Wg = ws + 8628864;

    ushort_t* in1p  = (ushort_t*)R1;
    ushort_t* c1out = (ushort_t*)R2;
    ushort_t* p1out = (ushort_t*)R3;
    ushort_t* c2out = (ushort_t*)R1;
    ushort_t* p2out = (ushort_t*)R2;
    ushort_t* c3out = (ushort_t*)(R2 + 775200);
    ushort_t* c4out = (ushort_t*)R1;
    ushort_t* c5out = (ushort_t*)R3;
    ushort_t* WT    = (ushort_t*)Wg;

    // ---- conv stack (tiled weight layout) ----
    zfill_k<<<(965500 + 255) / 256, 256, 0, stream>>>((float4*)R1, 965500);
    prep1_k<<<(BATCH * H0 * W0 + 255) / 256, 256, 0, stream>>>(search, exemp, in1p);
    wprep_k<<<(4352 + 255) / 256, 256, 0, stream>>>(aw1, WT, 11, 12, 11, 4, 3, 17, 4352);
    conv_mfma3<4, false><<<dim3(106, 1, BATCH), 256, 0, stream>>>(
        in1p, WT, ab1, c1out, HP1, WP1, 4, W1, H1 * W1, 17, 12, H1, W1, 0, 64);
    zfill_k<<<(270504 + 255) / 256, 256, 0, stream>>>((float4*)R3, 270504);
    pool_nhwc<<<(BATCH * 64 * H1P * W1P + 255) / 256, 256, 0, stream>>>(
        c1out, p1out, 64, H1, W1, H1P, W1P, 51, 39, 2);
    wprep_k<<<(38400 + 255) / 256, 256, 0, stream>>>(aw2, WT, 5, 5, 5, 64, 64, 50, 38400);
    conv_mfma3<1, true><<<dim3(26, 3, BATCH), 256, 0, stream>>>(
        p1out, WT, ab2, c2out, 51, 39, 64, W1P, H1P * W1P, 50, 5, H1P, W1P, 0, 192);
    zfill_k<<<(581400 + 255) / 256, 256, 0, stream>>>((float4*)R2, 581400);
    pool_nhwc<<<(BATCH * 192 * H2P * W2P + 255) / 256, 256, 0, stream>>>(
        c2out, p2out, 192, H1P, W1P, H2P, W2P, 25, 19, 1);
    wprep_k<<<(82944 + 255) / 256, 256, 0, stream>>>(aw3, WT, 3, 3, 3, 192, 192, 54, 82944);
    conv_mfma3<1, true><<<dim3(7, 6, BATCH), 256, 0, stream>>>(
        p2out, WT, ab3, c3out, 25, 19, 192, W2P, H2P * W2P, 54, 3, 25, 19, 1, 384);
    zfill_k<<<(258400 + 255) / 256, 256, 0, stream>>>((float4*)R1, 258400);
    wprep_k<<<(110592 + 255) / 256, 256, 0, stream>>>(aw4, WT, 3, 3, 3, 384, 384, 108, 110592);
    conv_mfma3<1, true><<<dim3(7, 4, BATCH), 256, 0, stream>>>(
        c3out, WT, ab4, c4out, 25, 19, 384, W2P, H2P * W2P, 108, 3, 25, 19, 1, 256);
    wprep_k<<<(73728 + 255) / 256, 256, 0, stream>>>(aw5, WT, 3, 3, 3, 256, 256, 72, 73728);
    conv_mfma3<1, true><<<dim3(7, 4, BATCH), 256, 0, stream>>>(
        c4out, WT, ab5, c5out, 25, 19, 256, W2P, H2P * W2P, 72, 3, H2P, W2P, 0, 256);

    // ---- tail region layout in R1 ----
    float*    P      = R1 + 2417664;
    ushort_t* PB     = (ushort_t*)(R1 + 2800640);
    ushort_t* XfPad  = (ushort_t*)(R1 + 2992128);   // rows 0 & 89 zeroed by first R1 zfill
    float*    xc     = R1 + 3003648;

    ushort_t* WS1T = (ushort_t*)Wg;
    ushort_t* WS2T = (ushort_t*)(Wg + 65536);
    ushort_t* WCDT = (ushort_t*)(Wg + 131072);
    wprep_gemm_k<<<(57344 + 255) / 256, 256, 0, stream>>>(ws1, ws2, wcd, WS1T, WS2T, WCDT);

    pool5_k<<<(BATCH * 256 * MM + 255) / 256, 256, 0, stream>>>(c5out, P, PB, XfPad);
    float* Xf2 = P;

    float* v_   = R1 + 0;
    float* xhat = R1 + 1024;
    float* Y1   = R1 + 23552;
    float* S1   = R1 + 744448;
    ushort_t* h1b = (ushort_t*)(R1 + 752640);
    float* Y2   = R1 + 1473536;
    float* S2   = R1 + 1833984;
    float* h2   = R1 + 1838080;
    float* V1   = R1 + 2198528;
    float* Vx   = R1 + 2221056;
    float* G    = R1 + 2243584;
    float* Hh   = R1 + 2266112;
    float* A2   = R1 + 2296832;
    float* t1   = R1 + 2305024;
    float* c1   = R1 + 2338816;
    float* t2   = R1 + 2372608;
    float* V2m  = R1 + 2395136;

    gemm_mfma3<0, true, false><<<dim3(2, 4), 256, 0, stream>>>(
        XfPad, WCDT, bcd, xc, 256, MM, 24, 1, MM);
    vmax_k<<<4, 64, 0, stream>>>(xc, v_);
    xhat_k<<<(DD * MM + 255) / 256, 256, 0, stream>>>(v_, wt, bt, xhat);

    gemm_mfma3<1, false, true><<<dim3(22, 8), 256, 0, stream>>>(
        PB, WS1T, nullptr, Y1, 256, TM, 8, 512, 1);
    s1_k<<<(T_EX * 512 + 255) / 256, 256, 0, stream>>>(Y1, S1);
    h1_k<<<(TM * 512 + 255) / 256, 256, 0, stream>>>(Y1, S1, bs1, h1b);
    gemm_mfma3<0, false, true><<<dim3(22, 4), 256, 0, stream>>>(
        h1b, WS2T, nullptr, Y2, 512, TM, 16, 256, 1);
    s2_k<<<(T_EX * 256 + 255) / 256, 256, 0, stream>>>(Y2, S2);
    h2_k<<<(TM * 256 + 255) / 256, 256, 0, stream>>>(Y2, S2, bs2, h2);
    v1vx_k<<<(DD * MM + 255) / 256, 256, 0, stream>>>(h2, xhat, V1, Vx);

    lin88_k<<<dim3((DD * MM + 255) / 256, 2), 256, 0, stream>>>(wg, bg, wh, bh, Vx, G, Hh);
    smsm_k<<<MM, 128, 0, stream>>>(Hh, G, A2);

    t1_k<<<(MM * 384 + 255) / 256, 256, 0, stream>>>(V1, wc1, t1);
    c1_k<<<(MM * 384 + 255) / 256, 256, 0, stream>>>(A2, t1, bc1, c1);
    t2_k<<<(MM * 256 + 255) / 256, 256, 0, stream>>>(c1, wc2, t2);
    v2_k<<<(MM * 256 + 255) / 256, 256, 0, stream>>>(A2, t2, bc2, V2m);

    final_k<<<1, 256, 0, stream>>>(Xf2, V2m, (float*)d_out);
}

// Round 9
// 590.511 us; speedup vs baseline: 1.5234x; 1.0218x over previous
//
#include <hip/hip_runtime.h>
#include <hip/hip_bf16.h>
#include <math.h>

// ---------- dims ----------
#define BATCH 17
#define T_EX 16
#define H0 383
#define W0 287
#define C1 64
#define H1 95
#define W1 71
#define H1P 47
#define W1P 35
#define C2 192
#define H2P 23
#define W2P 17
#define C3 384
#define C45 256
#define H5P 11
#define W5P 8
#define DD 256
#define MM 88
#define TM 1408

#define HP1 389
#define WP1 292

typedef unsigned short ushort_t;
typedef __attribute__((ext_vector_type(8))) short short8;
typedef __attribute__((ext_vector_type(4))) float f32x4;

__device__ __forceinline__ float lrelu(float v) { return v > 0.f ? v : 0.01f * v; }

__device__ __forceinline__ ushort_t f2bf(float f) {
    unsigned int u = __float_as_uint(f);
    unsigned int r = (u + 0x7fffu + ((u >> 16) & 1u)) >> 16;
    return (ushort_t)r;
}
__device__ __forceinline__ float b2f(ushort_t b) {
    return __uint_as_float(((unsigned int)b) << 16);
}
__device__ __forceinline__ short8 ld16(const ushort_t* p) { return *(const short8*)p; }
__device__ __forceinline__ short8 ld2x8(const ushort_t* p) {
    union { uint2 u[2]; short8 s; } uu;
    uu.u[0] = *(const uint2*)p;
    uu.u[1] = *(const uint2*)(p + 4);
    return uu.s;
}

// ---------- zero fill ----------
__global__ void zfill_k(float4* __restrict__ p, int n4) {
    int idx = blockIdx.x * 256 + threadIdx.x;
    if (idx < n4) p[idx] = (float4){0.f, 0.f, 0.f, 0.f};
}

// ---------- conv1 input prep: fp32 NCHW -> bf16 NHWC padded (C=4, pad 2) ----------
__global__ void prep1_k(const float* __restrict__ search, const float* __restrict__ exemp,
                        ushort_t* __restrict__ out) {
    int idx = blockIdx.x * 256 + threadIdx.x;
    if (idx >= BATCH * H0 * W0) return;
    int ix = idx % W0; int t = idx / W0;
    int iy = t % H0; int b = t / H0;
    const float* src = (b == 0) ? search : exemp + (size_t)(b - 1) * 3 * H0 * W0;
    const int hw = H0 * W0;
    float v0 = src[iy * W0 + ix];
    float v1 = src[hw + iy * W0 + ix];
    float v2 = src[2 * hw + iy * W0 + ix];
    ushort4 o;
    o.x = f2bf(v0); o.y = f2bf(v1); o.z = f2bf(v2); o.w = 0;
    *(ushort4*)&out[(((size_t)b * HP1 + iy + 2) * WP1 + ix + 2) * 4] = o;
}

// ---------- conv weight prep: OIHW fp32 -> bf16 MFMA tiles, K-order (ky,kx,ic) ----------
__global__ void wprep_k(const float* __restrict__ w, ushort_t* __restrict__ out,
                        int KH, int KWl, int KWr, int CINl, int CINr,
                        int NKS, int nch) {
    int idx = blockIdx.x * 256 + threadIdx.x;
    if (idx >= nch) return;
    int c = idx & 255;
    int rest = idx >> 8;
    int ks = rest % NKS;
    int ocb = rest / NKS;
    int k8 = c >> 6, m = c & 63;
    int oc = ocb * 64 + m;
    int KWC = KWl * CINl;
    ushort_t* o = out + (size_t)idx * 8;
#pragma unroll
    for (int j = 0; j < 8; ++j) {
        int kg = ks * 32 + k8 * 8 + j;
        int ky = kg / KWC; int rem = kg - ky * KWC;
        int kx = rem / CINl; int ic = rem - kx * CINl;
        float v = 0.f;
        if (ky < KH && kx < KWr && ic < CINr)
            v = w[(((size_t)oc * CINr + ic) * KH + ky) * KWr + kx];
        o[j] = f2bf(v);
    }
}

// ---------- fused gemm weight prep (ws1 | ws2 | wcd), tiled layout ----------
__global__ void wprep_gemm_k(const float* __restrict__ ws1, const float* __restrict__ ws2,
                             const float* __restrict__ wcd, ushort_t* __restrict__ WS1T,
                             ushort_t* __restrict__ WS2T, ushort_t* __restrict__ WCDT) {
    int idx = blockIdx.x * 256 + threadIdx.x;
    const float* src; ushort_t* dst; int NKS, mode = 0, sa = 1, sk = 0, base;
    if (idx < 16384)       { src = ws1; dst = WS1T; NKS = 8;  sk = 512; base = idx; }
    else if (idx < 32768)  { src = ws2; dst = WS2T; NKS = 16; sk = 256; base = idx - 16384; }
    else if (idx < 57344)  { src = wcd; dst = WCDT; NKS = 24; mode = 1; base = idx - 32768; }
    else return;
    int c = base & 255;
    int rest = base >> 8;
    int ks = rest % NKS;
    int ocb = rest / NKS;
    int k8 = c >> 6, m = c & 63;
    int oc = ocb * 64 + m;
    ushort_t* o = dst + (size_t)base * 8;
#pragma unroll
    for (int j = 0; j < 8; ++j) {
        int kg = ks * 32 + k8 * 8 + j;
        float v;
        if (mode == 0) v = src[(size_t)oc * sa + (size_t)kg * sk];
        else           v = src[(size_t)oc * 768 + (kg & 255) * 3 + (kg >> 8)];
        o[j] = f2bf(v);
    }
}

// ====================================================================
// bf16 MFMA implicit-GEMM conv, DEEP pipeline (3-step prefetch):
//  - A fragments direct from global (tiled layout), 3-deep reg queue
//  - B gathered to 3-deep reg queue; ds_write 2 steps after load;
//    2-buffer LDS; one barrier per step.
// ====================================================================
template <int STRIDE, bool A16>
__global__ __launch_bounds__(256) void conv_mfma4(
    const ushort_t* __restrict__ inp, const ushort_t* __restrict__ wt,
    const float* __restrict__ bias, ushort_t* __restrict__ out,
    int Hp, int Wp, int C, int Wout, int HW, int NKS, int KWl,
    int OHp, int OWp, int OPAD, int COUT) {
    const int tid = threadIdx.x;
    const int wv = tid >> 6, lane = tid & 63;
    const int quad = lane >> 4, l16 = lane & 15;
    const int n_blk = blockIdx.x * 64;
    const int ocb = blockIdx.y;
    const int b = blockIdx.z;

    __shared__ ushort_t Bs[2][2048];
    __shared__ int offs[448];

    const int KWC = KWl * C;
    for (int g = tid; g < NKS * 4; g += 256) {
        int kg = g * 8;
        int ky = kg / KWC; int rem = kg - ky * KWC;
        int kx = rem / C; int c8 = rem - kx * C;
        offs[g] = (ky * Wp + kx) * C + c8;
    }

    const ushort_t* inb = inp + (size_t)b * Hp * Wp * C;
    int n_g = n_blk + lane;
    int n_gc = n_g < HW ? n_g : HW - 1;
    int oy = n_gc / Wout, ox = n_gc - oy * Wout;
    const int base0 = (oy * STRIDE * Wp + ox * STRIDE) * C;

    f32x4 acc[4];
#pragma unroll
    for (int cn = 0; cn < 4; ++cn) acc[cn] = (f32x4){0.f, 0.f, 0.f, 0.f};

    const ushort_t* wblk = wt + (size_t)ocb * NKS * 2048;
    const int afrag = (quad * 64 + wv * 16 + l16) * 8;

    __syncthreads();   // offs ready

    // ---- prologue: A[0..2], B[0..2] in flight; B[0] staged ----
    short8 aU  = ld16(wblk + afrag);
    short8 aQ1 = ld16(wblk + 1 * 2048 + afrag);
    short8 aQ2 = ld16(wblk + 2 * 2048 + afrag);
    short8 b0;
    {
        const ushort_t* s = inb + base0 + offs[wv];
        b0 = A16 ? ld16(s) : ld2x8(s);
    }
    short8 bQ0, bQ1;
    {
        const ushort_t* s1 = inb + base0 + offs[4 + wv];
        bQ0 = A16 ? ld16(s1) : ld2x8(s1);
        const ushort_t* s2 = inb + base0 + offs[8 + wv];
        bQ1 = A16 ? ld16(s2) : ld2x8(s2);
    }
    *(short8*)&Bs[0][tid * 8] = b0;
    __syncthreads();

    for (int ks = 0; ks < NKS; ++ks) {
        const int cur = ks & 1, nxt = cur ^ 1;
        // stage B for step ks+1 (loaded at step ks-2 -> vmcnt satisfied)
        if (ks + 1 < NKS) *(short8*)&Bs[nxt][tid * 8] = bQ0;
        // issue loads for step ks+3
        short8 aN, bN;
        if (ks + 3 < NKS) {
            aN = ld16(wblk + (ks + 3) * 2048 + afrag);
            const ushort_t* s = inb + base0 + offs[(ks + 3) * 4 + wv];
            bN = A16 ? ld16(s) : ld2x8(s);
        }
        // compute step ks
#pragma unroll
        for (int cn = 0; cn < 4; ++cn) {
            const short8 bfr = *(const short8*)&Bs[cur][(quad * 64 + cn * 16 + l16) * 8];
            acc[cn] = __builtin_amdgcn_mfma_f32_16x16x32_bf16(aU, bfr, acc[cn], 0, 0, 0);
        }
        // rotate queues
        aU = aQ1; aQ1 = aQ2; aQ2 = aN;
        bQ0 = bQ1; bQ1 = bN;
        __syncthreads();
    }

    const int oc0 = ocb * 64 + wv * 16 + quad * 4;
    const float bi0 = bias[oc0], bi1 = bias[oc0 + 1], bi2 = bias[oc0 + 2], bi3 = bias[oc0 + 3];
#pragma unroll
    for (int cn = 0; cn < 4; ++cn) {
        int n = n_blk + cn * 16 + l16;
        if (n < HW) {
            int y = n / Wout, x = n - y * Wout;
            size_t base = (((size_t)b * OHp + y + OPAD) * OWp + x + OPAD) * COUT + oc0;
            ushort4 o;
            o.x = f2bf(fmaxf(acc[cn][0] + bi0, 0.f));
            o.y = f2bf(fmaxf(acc[cn][1] + bi1, 0.f));
            o.z = f2bf(fmaxf(acc[cn][2] + bi2, 0.f));
            o.w = f2bf(fmaxf(acc[cn][3] + bi3, 0.f));
            *(ushort4*)&out[base] = o;
        }
    }
}

// ====================================================================
// Generic bf16 MFMA GEMM: A direct from global (tiled), B LDS dbuf.
// ====================================================================
template <int MODE, bool HASBIAS, bool SC1>
__global__ __launch_bounds__(256) void gemm_mfma3(
    const ushort_t* __restrict__ Bsrc, const ushort_t* __restrict__ wt,
    const float* __restrict__ bias, float* __restrict__ out,
    int RS, int N, int NKS, int sn, int sc) {
    const int tid = threadIdx.x;
    const int wv = tid >> 6, lane = tid & 63;
    const int quad = lane >> 4, l16 = lane & 15;
    const int n_blk = blockIdx.x * 64;
    const int ocb = blockIdx.y;

    __shared__ ushort_t Bs[2][2048];

    int n_g = n_blk + lane;
    int n_gc = n_g < N ? n_g : N - 1;
    int row = (MODE == 1) ? (1 + (n_gc & 15)) * MM + (n_gc >> 4) : n_gc;
    const size_t base0 = (size_t)row * RS;

    f32x4 acc[4];
#pragma unroll
    for (int cn = 0; cn < 4; ++cn) acc[cn] = (f32x4){0.f, 0.f, 0.f, 0.f};

    const ushort_t* wblk = wt + (size_t)ocb * NKS * 2048;
    const int afrag = (quad * 64 + wv * 16 + l16) * 8;

    short8 a0 = ld16(wblk + afrag);
    *(short8*)&Bs[0][tid * 8] = ld16(Bsrc + base0 + wv * 8);
    __syncthreads();

    for (int ks = 0; ks < NKS; ++ks) {
        const int cur = ks & 1, nxt = cur ^ 1;
        short8 a1, bn;
        const bool more = (ks + 1 < NKS);
        if (more) {
            a1 = ld16(wblk + (ks + 1) * 2048 + afrag);
            bn = ld16(Bsrc + base0 + (ks + 1) * 32 + wv * 8);
        }
#pragma unroll
        for (int cn = 0; cn < 4; ++cn) {
            const short8 bfr = *(const short8*)&Bs[cur][(quad * 64 + cn * 16 + l16) * 8];
            acc[cn] = __builtin_amdgcn_mfma_f32_16x16x32_bf16(a0, bfr, acc[cn], 0, 0, 0);
        }
        if (more) *(short8*)&Bs[nxt][tid * 8] = bn;
        a0 = a1;
        __syncthreads();
    }

    const int oc0 = ocb * 64 + wv * 16 + quad * 4;
    float bb[4] = {0.f, 0.f, 0.f, 0.f};
    if (HASBIAS) { bb[0] = bias[oc0]; bb[1] = bias[oc0+1]; bb[2] = bias[oc0+2]; bb[3] = bias[oc0+3]; }
#pragma unroll
    for (int cn = 0; cn < 4; ++cn) {
        int n = n_blk + cn * 16 + l16;
        if (n < N) {
            if (SC1) {
                float4 o;
                o.x = acc[cn][0] + bb[0]; o.y = acc[cn][1] + bb[1];
                o.z = acc[cn][2] + bb[2]; o.w = acc[cn][3] + bb[3];
                *(float4*)&out[(size_t)n * sn + oc0] = o;
            } else {
#pragma unroll
                for (int reg = 0; reg < 4; ++reg)
                    out[(size_t)n * sn + (size_t)(oc0 + reg) * sc] = acc[cn][reg] + bb[reg];
            }
        }
    }
}

// ---------- maxpool k3 s2 VALID, NHWC bf16 ----------
__global__ void pool_nhwc(const ushort_t* __restrict__ in, ushort_t* __restrict__ out,
                          int C, int Hin, int Win, int Hout, int Wout,
                          int OHp, int OWp, int OPAD) {
    int total = BATCH * C * Hout * Wout;
    int idx = blockIdx.x * 256 + threadIdx.x;
    if (idx >= total) return;
    int c = idx % C; int r = idx / C;
    int x = r % Wout; r /= Wout;
    int y = r % Hout; int b = r / Hout;
    const int rs = Win * C;
    const ushort_t* p = in + (((size_t)b * Hin + 2 * y) * Win + 2 * x) * C + c;
    float m = b2f(p[0]);
    m = fmaxf(m, b2f(p[C])); m = fmaxf(m, b2f(p[2 * C]));
    m = fmaxf(m, b2f(p[rs])); m = fmaxf(m, b2f(p[rs + C])); m = fmaxf(m, b2f(p[rs + 2 * C]));
    m = fmaxf(m, b2f(p[2 * rs])); m = fmaxf(m, b2f(p[2 * rs + C])); m = fmaxf(m, b2f(p[2 * rs + 2 * C]));
    out[(((size_t)b * OHp + y + OPAD) * OWp + x + OPAD) * C + c] = f2bf(m);
}

// ---------- pool5: NHWC bf16 -> P fp32 [b][m][d] + PB bf16 + XfPad ----------
__global__ void pool5_k(const ushort_t* __restrict__ in, float* __restrict__ P,
                        ushort_t* __restrict__ PB, ushort_t* __restrict__ XfPad) {
    int total = BATCH * 256 * MM;
    int idx = blockIdx.x * 256 + threadIdx.x;
    if (idx >= total) return;
    int c = idx % 256; int r = idx / 256;
    int x = r % W5P; r /= W5P;
    int y = r % H5P; int b = r / H5P;
    const int rs = W2P * 256;
    const ushort_t* p = in + (((size_t)b * H2P + 2 * y) * W2P + 2 * x) * 256 + c;
    float m = b2f(p[0]);
    m = fmaxf(m, b2f(p[256])); m = fmaxf(m, b2f(p[512]));
    m = fmaxf(m, b2f(p[rs])); m = fmaxf(m, b2f(p[rs + 256])); m = fmaxf(m, b2f(p[rs + 512]));
    m = fmaxf(m, b2f(p[2 * rs])); m = fmaxf(m, b2f(p[2 * rs + 256])); m = fmaxf(m, b2f(p[2 * rs + 512]));
    int mm = y * W5P + x;
    size_t o = ((size_t)b * MM + mm) * 256 + c;
    P[o] = m;
    ushort_t mb = f2bf(m);
    PB[o] = mb;
    if (b == 0) XfPad[(size_t)(mm + 1) * 256 + c] = mb;
}

// ---------- v[c] = max_m xc[c*88+m] ----------
__global__ void vmax_k(const float* __restrict__ xc, float* __restrict__ v) {
    int c = blockIdx.x * 64 + threadIdx.x;
    float m = -INFINITY;
    for (int j = 0; j < MM; ++j) m = fmaxf(m, xc[(size_t)c * MM + j]);
    v[c] = m;
}

__global__ void xhat_k(const float* __restrict__ v, const float* __restrict__ wt,
                       const float* __restrict__ bt, float* __restrict__ xhat) {
    __shared__ float lv[256];
    for (int j = threadIdx.x; j < 256; j += 256) lv[j] = v[j];
    __syncthreads();
    int idx = blockIdx.x * 256 + threadIdx.x;
    if (idx >= DD * MM) return;
    int k = idx % MM, o = idx / MM;
    float acc = bt[o];
    for (int i = 0; i < 256; ++i) acc = fmaf(lv[i], wt[(i * 256 + o) * MM + k], acc);
    xhat[idx] = acc;
}

__global__ void s1_k(const float* __restrict__ Y1, float* __restrict__ S1) {
    int idx = blockIdx.x * 256 + threadIdx.x;
    if (idx >= T_EX * 512) return;
    int c = idx % 512, t = idx / 512;
    float acc = 0.f;
    for (int m = 0; m < MM; ++m) acc += Y1[(m * T_EX + t) * 512 + c];
    S1[idx] = acc;
}

__global__ void h1_k(const float* __restrict__ Y1, const float* __restrict__ S1,
                     const float* __restrict__ bs1, ushort_t* __restrict__ h1b) {
    int idx = blockIdx.x * 256 + threadIdx.x;
    if (idx >= TM * 512) return;
    int c = idx % 512; int n = idx / 512;
    int t = n % T_EX;
    float val = S1[t * 512 + c] + bs1[c];
    if (t == 0) val -= Y1[idx];
    h1b[idx] = f2bf(lrelu(val));
}

__global__ void s2_k(const float* __restrict__ Y2, float* __restrict__ S2) {
    int idx = blockIdx.x * 256 + threadIdx.x;
    if (idx >= T_EX * 256) return;
    int c = idx % 256, t = idx / 256;
    float acc = 0.f;
    for (int m = 0; m < MM; ++m) acc += Y2[(m * T_EX + t) * 256 + c];
    S2[idx] = acc;
}

__global__ void h2_k(const float* __restrict__ Y2, const float* __restrict__ S2,
                     const float* __restrict__ bs2, float* __restrict__ h2) {
    int idx = blockIdx.x * 256 + threadIdx.x;
    if (idx >= TM * 256) return;
    int c = idx % 256; int n = idx / 256;
    int t = n % T_EX;
    float val = S2[t * 256 + c] + bs2[c];
    if (t == 0) val -= Y2[idx];
    h2[idx] = lrelu(val);
}

__global__ void v1vx_k(const float* __restrict__ h2, const float* __restrict__ xhat,
                       float* __restrict__ V1, float* __restrict__ Vx) {
    int idx = blockIdx.x * 256 + threadIdx.x;
    if (idx >= DD * MM) return;
    int m = idx % MM, d = idx / MM;
    float mx = -INFINITY;
    for (int t = 0; t < T_EX; ++t) mx = fmaxf(mx, h2[(m * T_EX + t) * 256 + d]);
    V1[idx] = mx;
    Vx[idx] = mx + xhat[idx];
}

__global__ void lin88_k(const float* __restrict__ Wg, const float* __restrict__ bg,
                        const float* __restrict__ Wh, const float* __restrict__ bh,
                        const float* __restrict__ Vin, float* __restrict__ Gout,
                        float* __restrict__ Hout) {
    int idx = blockIdx.x * 256 + threadIdx.x;
    if (idx >= DD * MM) return;
    const float* W = blockIdx.y ? Wh : Wg;
    const float* bias = blockIdx.y ? bh : bg;
    float* out = blockIdx.y ? Hout : Gout;
    int m = idx % MM, o = idx / MM;
    const float* wr = W + o * 256;
    float acc = bias[o];
    for (int i = 0; i < 256; ++i) acc = fmaf(wr[i], Vin[i * MM + m], acc);
    out[idx] = acc;
}

// ---------- fused Smat row + softmax ----------
__global__ void smsm_k(const float* __restrict__ Hh, const float* __restrict__ G,
                       float* __restrict__ A2) {
    int j = blockIdx.x;
    int tid = threadIdx.x;   // 128
    __shared__ float row[96];
    __shared__ float red[128];
    for (int i = tid; i < MM; i += 128) {
        float acc = 0.f;
        for (int c = 0; c < 256; ++c) acc = fmaf(Hh[c * MM + j], G[c * MM + i], acc);
        row[i] = acc;
    }
    __syncthreads();
    float val = (tid < MM) ? row[tid] : -INFINITY;
    red[tid] = val; __syncthreads();
    for (int s = 64; s > 0; s >>= 1) {
        if (tid < s) red[tid] = fmaxf(red[tid], red[tid + s]);
        __syncthreads();
    }
    float mx = red[0]; __syncthreads();
    float e = (tid < MM) ? expf(val - mx) : 0.f;
    red[tid] = e; __syncthreads();
    for (int s = 64; s > 0; s >>= 1) {
        if (tid < s) red[tid] += red[tid + s];
        __syncthreads();
    }
    float inv = 1.f / red[0];
    if (tid < MM) A2[j * MM + tid] = e * inv;
}

__global__ void t1_k(const float* __restrict__ V1, const float* __restrict__ wc1,
                     float* __restrict__ t1) {
    int idx = blockIdx.x * 256 + threadIdx.x;
    if (idx >= MM * 384) return;
    int c = idx % 384, m = idx / 384;
    float acc = 0.f;
    for (int d = 0; d < 256; ++d) acc = fmaf(V1[d * MM + m], wc1[d * 384 + c], acc);
    t1[idx] = acc;
}

__global__ void c1_k(const float* __restrict__ A2, const float* __restrict__ t1,
                     const float* __restrict__ bc1, float* __restrict__ c1) {
    int idx = blockIdx.x * 256 + threadIdx.x;
    if (idx >= MM * 384) return;
    int c = idx % 384, j = idx / 384;
    float acc = bc1[c];
    for (int i = 0; i < MM; ++i) acc = fmaf(A2[j * MM + i], t1[i * 384 + c], acc);
    c1[idx] = lrelu(acc);
}

__global__ void t2_k(const float* __restrict__ c1, const float* __restrict__ wc2,
                     float* __restrict__ t2) {
    int idx = blockIdx.x * 256 + threadIdx.x;
    if (idx >= MM * 256) return;
    int c = idx % 256, m = idx / 256;
    const float* cr = c1 + m * 384;
    float acc = 0.f;
    for (int d = 0; d < 384; ++d) acc = fmaf(cr[d], wc2[d * 256 + c], acc);
    t2[idx] = acc;
}

__global__ void v2_k(const float* __restrict__ A2, const float* __restrict__ t2,
                     const float* __restrict__ bc2, float* __restrict__ V2m) {
    int idx = blockIdx.x * 256 + threadIdx.x;
    if (idx >= MM * 256) return;
    int c = idx % 256, j = idx / 256;
    float acc = bc2[c];
    for (int i = 0; i < MM; ++i) acc = fmaf(A2[j * MM + i], t2[i * 256 + c], acc);
    V2m[idx] = lrelu(acc);
}

__global__ void final_k(const float* __restrict__ Xf2, const float* __restrict__ V2m,
                        float* __restrict__ out) {
    __shared__ float red[256];
    float acc = 0.f;
    for (int idx = threadIdx.x; idx < DD * MM; idx += 256)
        acc = fmaf(Xf2[idx], V2m[idx], acc);
    red[threadIdx.x] = acc; __syncthreads();
    for (int s = 128; s > 0; s >>= 1) {
        if (threadIdx.x < s) red[threadIdx.x] += red[threadIdx.x + s];
        __syncthreads();
    }
    if (threadIdx.x == 0) out[0] = red[0];
}

extern "C" void kernel_launch(void* const* d_in, const int* in_sizes, int n_in,
                              void* d_out, int out_size, void* d_ws, size_t ws_size,
                              hipStream_t stream) {
    const float* search = (const float*)d_in[0];
    const float* exemp  = (const float*)d_in[1];
    const float* aw1 = (const float*)d_in[2];  const float* ab1 = (const float*)d_in[3];
    const float* aw2 = (const float*)d_in[4];  const float* ab2 = (const float*)d_in[5];
    const float* aw3 = (const float*)d_in[6];  const float* ab3 = (const float*)d_in[7];
    const float* aw4 = (const float*)d_in[8];  const float* ab4 = (const float*)d_in[9];
    const float* aw5 = (const float*)d_in[10]; const float* ab5 = (const float*)d_in[11];
    const float* wcd = (const float*)d_in[12]; const float* bcd = (const float*)d_in[13];
    const float* wt  = (const float*)d_in[14]; const float* bt  = (const float*)d_in[15];
    const float* ws1 = (const float*)d_in[16]; const float* bs1 = (const float*)d_in[17];
    const float* ws2 = (const float*)d_in[18]; const float* bs2 = (const float*)d_in[19];
    const float* wg  = (const float*)d_in[20]; const float* bg  = (const float*)d_in[21];
    const float* wh  = (const float*)d_in[22]; const float* bh  = (const float*)d_in[23];
    const float* wc1 = (const float*)d_in[24]; const float* bc1 = (const float*)d_in[25];
    const float* wc2 = (const float*)d_in[26]; const float* bc2 = (const float*)d_in[27];

    float* ws = (float*)d_ws;
    float* R1 = ws;
    float* R2 = ws + 3870720;
    float* R3 = ws + 7544832;
    float* Wg = ws + 8628864;

    ushort_t* in1p  = (ushort_t*)R1;
    ushort_t* c1out = (ushort_t*)R2;
    ushort_t* p1out = (ushort_t*)R3;
    ushort_t* c2out = (ushort_t*)R1;
    ushort_t* p2out = (ushort_t*)R2;
    ushort_t* c3out = (ushort_t*)(R2 + 775200);
    ushort_t* c4out = (ushort_t*)R1;
    ushort_t* c5out = (ushort_t*)R3;
    ushort_t* WT    = (ushort_t*)Wg;

    // ---- conv stack (tiled weight layout, deep-pipelined convs) ----
    zfill_k<<<(965500 + 255) / 256, 256, 0, stream>>>((float4*)R1, 965500);
    prep1_k<<<(BATCH * H0 * W0 + 255) / 256, 256, 0, stream>>>(search, exemp, in1p);
    wprep_k<<<(4352 + 255) / 256, 256, 0, stream>>>(aw1, WT, 11, 12, 11, 4, 3, 17, 4352);
    conv_mfma4<4, false><<<dim3(106, 1, BATCH), 256, 0, stream>>>(
        in1p, WT, ab1, c1out, HP1, WP1, 4, W1, H1 * W1, 17, 12, H1, W1, 0, 64);
    zfill_k<<<(270504 + 255) / 256, 256, 0, stream>>>((float4*)R3, 270504);
    pool_nhwc<<<(BATCH * 64 * H1P * W1P + 255) / 256, 256, 0, stream>>>(
        c1out, p1out, 64, H1, W1, H1P, W1P, 51, 39, 2);
    wprep_k<<<(38400 + 255) / 256, 256, 0, stream>>>(aw2, WT, 5, 5, 5, 64, 64, 50, 38400);
    conv_mfma4<1, true><<<dim3(26, 3, BATCH), 256, 0, stream>>>(
        p1out, WT, ab2, c2out, 51, 39, 64, W1P, H1P * W1P, 50, 5, H1P, W1P, 0, 192);
    zfill_k<<<(581400 + 255) / 256, 256, 0, stream>>>((float4*)R2, 581400);
    pool_nhwc<<<(BATCH * 192 * H2P * W2P + 255) / 256, 256, 0, stream>>>(
        c2out, p2out, 192, H1P, W1P, H2P, W2P, 25, 19, 1);
    wprep_k<<<(82944 + 255) / 256, 256, 0, stream>>>(aw3, WT, 3, 3, 3, 192, 192, 54, 82944);
    conv_mfma4<1, true><<<dim3(7, 6, BATCH), 256, 0, stream>>>(
        p2out, WT, ab3, c3out, 25, 19, 192, W2P, H2P * W2P, 54, 3, 25, 19, 1, 384);
    zfill_k<<<(258400 + 255) / 256, 256, 0, stream>>>((float4*)R1, 258400);
    wprep_k<<<(110592 + 255) / 256, 256, 0, stream>>>(aw4, WT, 3, 3, 3, 384, 384, 108, 110592);
    conv_mfma4<1, true><<<dim3(7, 4, BATCH), 256, 0, stream>>>(
        c3out, WT, ab4, c4out, 25, 19, 384, W2P, H2P * W2P, 108, 3, 25, 19, 1, 256);
    wprep_k<<<(73728 + 255) / 256, 256, 0, stream>>>(aw5, WT, 3, 3, 3, 256, 256, 72, 73728);
    conv_mfma4<1, true><<<dim3(7, 4, BATCH), 256, 0, stream>>>(
        c4out, WT, ab5, c5out, 25, 19, 256, W2P, H2P * W2P, 72, 3, H2P, W2P, 0, 256);

    // ---- tail region layout in R1 ----
    float*    P      = R1 + 2417664;
    ushort_t* PB     = (ushort_t*)(R1 + 2800640);
    ushort_t* XfPad  = (ushort_t*)(R1 + 2992128);   // rows 0 & 89 zeroed by first R1 zfill
    float*    xc     = R1 + 3003648;

    ushort_t* WS1T = (ushort_t*)Wg;
    ushort_t* WS2T = (ushort_t*)(Wg + 65536);
    ushort_t* WCDT = (ushort_t*)(Wg + 131072);
    wprep_gemm_k<<<(57344 + 255) / 256, 256, 0, stream>>>(ws1, ws2, wcd, WS1T, WS2T, WCDT);

    pool5_k<<<(BATCH * 256 * MM + 255) / 256, 256, 0, stream>>>(c5out, P, PB, XfPad);
    float* Xf2 = P;

    float* v_   = R1 + 0;
    float* xhat = R1 + 1024;
    float* Y1   = R1 + 23552;
    float* S1   = R1 + 744448;
    ushort_t* h1b = (ushort_t*)(R1 + 752640);
    float* Y2   = R1 + 1473536;
    float* S2   = R1 + 1833984;
    float* h2   = R1 + 1838080;
    float* V1   = R1 + 2198528;
    float* Vx   = R1 + 2221056;
    float* G    = R1 + 2243584;
    float* Hh   = R1 + 2266112;
    float* A2   = R1 + 2296832;
    float* t1   = R1 + 2305024;
    float* c1   = R1 + 2338816;
    float* t2   = R1 + 2372608;
    float* V2m  = R1 + 2395136;

    gemm_mfma3<0, true, false><<<dim3(2, 4), 256, 0, stream>>>(
        XfPad, WCDT, bcd, xc, 256, MM, 24, 1, MM);
    vmax_k<<<4, 64, 0, stream>>>(xc, v_);
    xhat_k<<<(DD * MM + 255) / 256, 256, 0, stream>>>(v_, wt, bt, xhat);

    gemm_mfma3<1, false, true><<<dim3(22, 8), 256, 0, stream>>>(
        PB, WS1T, nullptr, Y1, 256, TM, 8, 512, 1);
    s1_k<<<(T_EX * 512 + 255) / 256, 256, 0, stream>>>(Y1, S1);
    h1_k<<<(TM * 512 + 255) / 256, 256, 0, stream>>>(Y1, S1, bs1, h1b);
    gemm_mfma3<0, false, true><<<dim3(22, 4), 256, 0, stream>>>(
        h1b, WS2T, nullptr, Y2, 512, TM, 16, 256, 1);
    s2_k<<<(T_EX * 256 + 255) / 256, 256, 0, stream>>>(Y2, S2);
    h2_k<<<(TM * 256 + 255) / 256, 256, 0, stream>>>(Y2, S2, bs2, h2);
    v1vx_k<<<(DD * MM + 255) / 256, 256, 0, stream>>>(h2, xhat, V1, Vx);

    lin88_k<<<dim3((DD * MM + 255) / 256, 2), 256, 0, stream>>>(wg, bg, wh, bh, Vx, G, Hh);
    smsm_k<<<MM, 128, 0, stream>>>(Hh, G, A2);

    t1_k<<<(MM * 384 + 255) / 256, 256, 0, stream>>>(V1, wc1, t1);
    c1_k<<<(MM * 384 + 255) / 256, 256, 0, stream>>>(A2, t1, bc1, c1);
    t2_k<<<(MM * 256 + 255) / 256, 256, 0, stream>>>(c1, wc2, t2);
    v2_k<<<(MM * 256 + 255) / 256, 256, 0, stream>>>(A2, t2, bc2, V2m);

    final_k<<<1, 256, 0, stream>>>(Xf2, V2m, (float*)d_out);
}

// Round 10
// 545.496 us; speedup vs baseline: 1.6491x; 1.0825x over previous
//
#include <hip/hip_runtime.h>
#include <hip/hip_bf16.h>
#include <math.h>

// ---------- dims ----------
#define BATCH 17
#define T_EX 16
#define H0 383
#define W0 287
#define C1 64
#define H1 95
#define W1 71
#define H1P 47
#define W1P 35
#define C2 192
#define H2P 23
#define W2P 17
#define C3 384
#define C45 256
#define H5P 11
#define W5P 8
#define DD 256
#define MM 88
#define TM 1408

#define HP1 389
#define WP1 292

typedef unsigned short ushort_t;
typedef __attribute__((ext_vector_type(8))) short short8;
typedef __attribute__((ext_vector_type(4))) float f32x4;

__device__ __forceinline__ float lrelu(float v) { return v > 0.f ? v : 0.01f * v; }

__device__ __forceinline__ ushort_t f2bf(float f) {
    unsigned int u = __float_as_uint(f);
    unsigned int r = (u + 0x7fffu + ((u >> 16) & 1u)) >> 16;
    return (ushort_t)r;
}
__device__ __forceinline__ float b2f(ushort_t b) {
    return __uint_as_float(((unsigned int)b) << 16);
}
__device__ __forceinline__ short8 ld16(const ushort_t* p) { return *(const short8*)p; }
__device__ __forceinline__ short8 ld2x8(const ushort_t* p) {
    union { uint2 u[2]; short8 s; } uu;
    uu.u[0] = *(const uint2*)p;
    uu.u[1] = *(const uint2*)(p + 4);
    return uu.s;
}
// async global -> LDS, 16B per lane; LDS dest = wave-uniform base + lane*16
__device__ __forceinline__ void async_cp16(ushort_t* l, const ushort_t* g) {
    __builtin_amdgcn_global_load_lds(
        (const __attribute__((address_space(1))) void*)g,
        (__attribute__((address_space(3))) void*)l, 16, 0, 0);
}

// ---------- zero fill ----------
__global__ void zfill_k(float4* __restrict__ p, int n4) {
    int idx = blockIdx.x * 256 + threadIdx.x;
    if (idx < n4) p[idx] = (float4){0.f, 0.f, 0.f, 0.f};
}

// ---------- conv1 input prep: fp32 NCHW -> bf16 NHWC padded (C=4, pad 2) ----------
__global__ void prep1_k(const float* __restrict__ search, const float* __restrict__ exemp,
                        ushort_t* __restrict__ out) {
    int idx = blockIdx.x * 256 + threadIdx.x;
    if (idx >= BATCH * H0 * W0) return;
    int ix = idx % W0; int t = idx / W0;
    int iy = t % H0; int b = t / H0;
    const float* src = (b == 0) ? search : exemp + (size_t)(b - 1) * 3 * H0 * W0;
    const int hw = H0 * W0;
    float v0 = src[iy * W0 + ix];
    float v1 = src[hw + iy * W0 + ix];
    float v2 = src[2 * hw + iy * W0 + ix];
    ushort4 o;
    o.x = f2bf(v0); o.y = f2bf(v1); o.z = f2bf(v2); o.w = 0;
    *(ushort4*)&out[(((size_t)b * HP1 + iy + 2) * WP1 + ix + 2) * 4] = o;
}

// ---------- conv weight prep: OIHW fp32 -> bf16 MFMA tiles, K-order (ky,kx,ic) ----------
__global__ void wprep_k(const float* __restrict__ w, ushort_t* __restrict__ out,
                        int KH, int KWl, int KWr, int CINl, int CINr,
                        int NKS, int nch) {
    int idx = blockIdx.x * 256 + threadIdx.x;
    if (idx >= nch) return;
    int c = idx & 255;
    int rest = idx >> 8;
    int ks = rest % NKS;
    int ocb = rest / NKS;
    int k8 = c >> 6, m = c & 63;
    int oc = ocb * 64 + m;
    int KWC = KWl * CINl;
    ushort_t* o = out + (size_t)idx * 8;
#pragma unroll
    for (int j = 0; j < 8; ++j) {
        int kg = ks * 32 + k8 * 8 + j;
        int ky = kg / KWC; int rem = kg - ky * KWC;
        int kx = rem / CINl; int ic = rem - kx * CINl;
        float v = 0.f;
        if (ky < KH && kx < KWr && ic < CINr)
            v = w[(((size_t)oc * CINr + ic) * KH + ky) * KWr + kx];
        o[j] = f2bf(v);
    }
}

// ---------- fused gemm weight prep (ws1 | ws2 | wcd), tiled layout ----------
__global__ void wprep_gemm_k(const float* __restrict__ ws1, const float* __restrict__ ws2,
                             const float* __restrict__ wcd, ushort_t* __restrict__ WS1T,
                             ushort_t* __restrict__ WS2T, ushort_t* __restrict__ WCDT) {
    int idx = blockIdx.x * 256 + threadIdx.x;
    const float* src; ushort_t* dst; int NKS, mode = 0, sa = 1, sk = 0, base;
    if (idx < 16384)       { src = ws1; dst = WS1T; NKS = 8;  sk = 512; base = idx; }
    else if (idx < 32768)  { src = ws2; dst = WS2T; NKS = 16; sk = 256; base = idx - 16384; }
    else if (idx < 57344)  { src = wcd; dst = WCDT; NKS = 24; mode = 1; base = idx - 32768; }
    else return;
    int c = base & 255;
    int rest = base >> 8;
    int ks = rest % NKS;
    int ocb = rest / NKS;
    int k8 = c >> 6, m = c & 63;
    int oc = ocb * 64 + m;
    ushort_t* o = dst + (size_t)base * 8;
#pragma unroll
    for (int j = 0; j < 8; ++j) {
        int kg = ks * 32 + k8 * 8 + j;
        float v;
        if (mode == 0) v = src[(size_t)oc * sa + (size_t)kg * sk];
        else           v = src[(size_t)oc * 768 + (kg & 255) * 3 + (kg >> 8)];
        o[j] = f2bf(v);
    }
}

// ====================================================================
// bf16 MFMA implicit-GEMM conv, m97-style: async global->LDS DMA for
// A and B tiles (BK=64 = two 32k tiles/step), double-buffered, one
// barrier per step; 32 MFMAs per barrier. conv1 (A16=false) stages B
// through registers (8B pairs unsupported by LDS-DMA).
// ====================================================================
template <int STRIDE, bool A16>
__global__ __launch_bounds__(256) void conv_mfma5(
    const ushort_t* __restrict__ inp, const ushort_t* __restrict__ wt,
    const float* __restrict__ bias, ushort_t* __restrict__ out,
    int Hp, int Wp, int C, int Wout, int HW, int NKS2, int KWl,
    int OHp, int OWp, int OPAD, int COUT) {
    const int tid = threadIdx.x;
    const int wv = tid >> 6, lane = tid & 63;
    const int quad = lane >> 4, l16 = lane & 15;
    const int n_blk = blockIdx.x * 64;
    const int ocb = blockIdx.y;
    const int b = blockIdx.z;

    __shared__ ushort_t As[2][4096];   // [buf][2 tiles x 2048 bf16] = 8 KB/buf
    __shared__ ushort_t Bs[2][4096];
    __shared__ int offs[432];

    const int KWC = KWl * C;
    for (int g = tid; g < NKS2 * 8; g += 256) {
        int kg = g * 8;
        int ky = kg / KWC; int rem = kg - ky * KWC;
        int kx = rem / C; int c8 = rem - kx * C;
        offs[g] = (ky * Wp + kx) * C + c8;
    }

    const ushort_t* inb = inp + (size_t)b * Hp * Wp * C;
    int n_g = n_blk + lane;
    int n_gc = n_g < HW ? n_g : HW - 1;
    int oy = n_gc / Wout, ox = n_gc - oy * Wout;
    const int base0 = (oy * STRIDE * Wp + ox * STRIDE) * C;

    f32x4 acc[4];
#pragma unroll
    for (int cn = 0; cn < 4; ++cn) acc[cn] = (f32x4){0.f, 0.f, 0.f, 0.f};

    const ushort_t* wblk = wt + (size_t)ocb * (size_t)NKS2 * 4096;

    __syncthreads();   // offs ready

    // ---- prologue: stage step 0 into buf 0 ----
    {
        const ushort_t* aS = wblk + tid * 8;
        async_cp16(&As[0][tid * 8], aS);
        async_cp16(&As[0][2048 + tid * 8], aS + 2048);
        const int o0 = offs[wv], o1 = offs[4 + wv];
        if (A16) {
            async_cp16(&Bs[0][tid * 8], inb + base0 + o0);
            async_cp16(&Bs[0][2048 + tid * 8], inb + base0 + o1);
        } else {
            *(short8*)&Bs[0][tid * 8] = ld2x8(inb + base0 + o0);
            *(short8*)&Bs[0][2048 + tid * 8] = ld2x8(inb + base0 + o1);
        }
    }
    __syncthreads();

    for (int ks2 = 0; ks2 < NKS2; ++ks2) {
        const int cur = ks2 & 1, nxt = cur ^ 1;
        // stage next step (async; in flight during the 32 MFMAs below)
        if (ks2 + 1 < NKS2) {
            const ushort_t* aS = wblk + (size_t)(ks2 + 1) * 4096 + tid * 8;
            async_cp16(&As[nxt][tid * 8], aS);
            async_cp16(&As[nxt][2048 + tid * 8], aS + 2048);
            const int o0 = offs[(ks2 + 1) * 8 + wv], o1 = offs[(ks2 + 1) * 8 + 4 + wv];
            if (A16) {
                async_cp16(&Bs[nxt][tid * 8], inb + base0 + o0);
                async_cp16(&Bs[nxt][2048 + tid * 8], inb + base0 + o1);
            } else {
                *(short8*)&Bs[nxt][tid * 8] = ld2x8(inb + base0 + o0);
                *(short8*)&Bs[nxt][2048 + tid * 8] = ld2x8(inb + base0 + o1);
            }
        }
        // compute: 2 half-tiles x 4 col-tiles = 32 MFMAs
#pragma unroll
        for (int h = 0; h < 2; ++h) {
            const short8 af = *(const short8*)&As[cur][h * 2048 + (quad * 64 + wv * 16 + l16) * 8];
#pragma unroll
            for (int cn = 0; cn < 4; ++cn) {
                const short8 bfr = *(const short8*)&Bs[cur][h * 2048 + (quad * 64 + cn * 16 + l16) * 8];
                acc[cn] = __builtin_amdgcn_mfma_f32_16x16x32_bf16(af, bfr, acc[cn], 0, 0, 0);
            }
        }
        __syncthreads();
    }

    const int oc0 = ocb * 64 + wv * 16 + quad * 4;
    const float bi0 = bias[oc0], bi1 = bias[oc0 + 1], bi2 = bias[oc0 + 2], bi3 = bias[oc0 + 3];
#pragma unroll
    for (int cn = 0; cn < 4; ++cn) {
        int n = n_blk + cn * 16 + l16;
        if (n < HW) {
            int y = n / Wout, x = n - y * Wout;
            size_t base = (((size_t)b * OHp + y + OPAD) * OWp + x + OPAD) * COUT + oc0;
            ushort4 o;
            o.x = f2bf(fmaxf(acc[cn][0] + bi0, 0.f));
            o.y = f2bf(fmaxf(acc[cn][1] + bi1, 0.f));
            o.z = f2bf(fmaxf(acc[cn][2] + bi2, 0.f));
            o.w = f2bf(fmaxf(acc[cn][3] + bi3, 0.f));
            *(ushort4*)&out[base] = o;
        }
    }
}

// ====================================================================
// Generic bf16 MFMA GEMM: A direct from global (tiled), B LDS dbuf.
// ====================================================================
template <int MODE, bool HASBIAS, bool SC1>
__global__ __launch_bounds__(256) void gemm_mfma3(
    const ushort_t* __restrict__ Bsrc, const ushort_t* __restrict__ wt,
    const float* __restrict__ bias, float* __restrict__ out,
    int RS, int N, int NKS, int sn, int sc) {
    const int tid = threadIdx.x;
    const int wv = tid >> 6, lane = tid & 63;
    const int quad = lane >> 4, l16 = lane & 15;
    const int n_blk = blockIdx.x * 64;
    const int ocb = blockIdx.y;

    __shared__ ushort_t Bs[2][2048];

    int n_g = n_blk + lane;
    int n_gc = n_g < N ? n_g : N - 1;
    int row = (MODE == 1) ? (1 + (n_gc & 15)) * MM + (n_gc >> 4) : n_gc;
    const size_t base0 = (size_t)row * RS;

    f32x4 acc[4];
#pragma unroll
    for (int cn = 0; cn < 4; ++cn) acc[cn] = (f32x4){0.f, 0.f, 0.f, 0.f};

    const ushort_t* wblk = wt + (size_t)ocb * NKS * 2048;
    const int afrag = (quad * 64 + wv * 16 + l16) * 8;

    short8 a0 = ld16(wblk + afrag);
    *(short8*)&Bs[0][tid * 8] = ld16(Bsrc + base0 + wv * 8);
    __syncthreads();

    for (int ks = 0; ks < NKS; ++ks) {
        const int cur = ks & 1, nxt = cur ^ 1;
        short8 a1, bn;
        const bool more = (ks + 1 < NKS);
        if (more) {
            a1 = ld16(wblk + (ks + 1) * 2048 + afrag);
            bn = ld16(Bsrc + base0 + (ks + 1) * 32 + wv * 8);
        }
#pragma unroll
        for (int cn = 0; cn < 4; ++cn) {
            const short8 bfr = *(const short8*)&Bs[cur][(quad * 64 + cn * 16 + l16) * 8];
            acc[cn] = __builtin_amdgcn_mfma_f32_16x16x32_bf16(a0, bfr, acc[cn], 0, 0, 0);
        }
        if (more) *(short8*)&Bs[nxt][tid * 8] = bn;
        a0 = a1;
        __syncthreads();
    }

    const int oc0 = ocb * 64 + wv * 16 + quad * 4;
    float bb[4] = {0.f, 0.f, 0.f, 0.f};
    if (HASBIAS) { bb[0] = bias[oc0]; bb[1] = bias[oc0+1]; bb[2] = bias[oc0+2]; bb[3] = bias[oc0+3]; }
#pragma unroll
    for (int cn = 0; cn < 4; ++cn) {
        int n = n_blk + cn * 16 + l16;
        if (n < N) {
            if (SC1) {
                float4 o;
                o.x = acc[cn][0] + bb[0]; o.y = acc[cn][1] + bb[1];
                o.z = acc[cn][2] + bb[2]; o.w = acc[cn][3] + bb[3];
                *(float4*)&out[(size_t)n * sn + oc0] = o;
            } else {
#pragma unroll
                for (int reg = 0; reg < 4; ++reg)
                    out[(size_t)n * sn + (size_t)(oc0 + reg) * sc] = acc[cn][reg] + bb[reg];
            }
        }
    }
}

// ---------- maxpool k3 s2 VALID, NHWC bf16 ----------
__global__ void pool_nhwc(const ushort_t* __restrict__ in, ushort_t* __restrict__ out,
                          int C, int Hin, int Win, int Hout, int Wout,
                          int OHp, int OWp, int OPAD) {
    int total = BATCH * C * Hout * Wout;
    int idx = blockIdx.x * 256 + threadIdx.x;
    if (idx >= total) return;
    int c = idx % C; int r = idx / C;
    int x = r % Wout; r /= Wout;
    int y = r % Hout; int b = r / Hout;
    const int rs = Win * C;
    const ushort_t* p = in + (((size_t)b * Hin + 2 * y) * Win + 2 * x) * C + c;
    float m = b2f(p[0]);
    m = fmaxf(m, b2f(p[C])); m = fmaxf(m, b2f(p[2 * C]));
    m = fmaxf(m, b2f(p[rs])); m = fmaxf(m, b2f(p[rs + C])); m = fmaxf(m, b2f(p[rs + 2 * C]));
    m = fmaxf(m, b2f(p[2 * rs])); m = fmaxf(m, b2f(p[2 * rs + C])); m = fmaxf(m, b2f(p[2 * rs + 2 * C]));
    out[(((size_t)b * OHp + y + OPAD) * OWp + x + OPAD) * C + c] = f2bf(m);
}

// ---------- pool5: NHWC bf16 -> P fp32 [b][m][d] + PB bf16 + XfPad ----------
__global__ void pool5_k(const ushort_t* __restrict__ in, float* __restrict__ P,
                        ushort_t* __restrict__ PB, ushort_t* __restrict__ XfPad) {
    int total = BATCH * 256 * MM;
    int idx = blockIdx.x * 256 + threadIdx.x;
    if (idx >= total) return;
    int c = idx % 256; int r = idx / 256;
    int x = r % W5P; r /= W5P;
    int y = r % H5P; int b = r / H5P;
    const int rs = W2P * 256;
    const ushort_t* p = in + (((size_t)b * H2P + 2 * y) * W2P + 2 * x) * 256 + c;
    float m = b2f(p[0]);
    m = fmaxf(m, b2f(p[256])); m = fmaxf(m, b2f(p[512]));
    m = fmaxf(m, b2f(p[rs])); m = fmaxf(m, b2f(p[rs + 256])); m = fmaxf(m, b2f(p[rs + 512]));
    m = fmaxf(m, b2f(p[2 * rs])); m = fmaxf(m, b2f(p[2 * rs + 256])); m = fmaxf(m, b2f(p[2 * rs + 512]));
    int mm = y * W5P + x;
    size_t o = ((size_t)b * MM + mm) * 256 + c;
    P[o] = m;
    ushort_t mb = f2bf(m);
    PB[o] = mb;
    if (b == 0) XfPad[(size_t)(mm + 1) * 256 + c] = mb;
}

// ---------- v[c] = max_m xc[c*88+m] ----------
__global__ void vmax_k(const float* __restrict__ xc, float* __restrict__ v) {
    int c = blockIdx.x * 64 + threadIdx.x;
    float m = -INFINITY;
    for (int j = 0; j < MM; ++j) m = fmaxf(m, xc[(size_t)c * MM + j]);
    v[c] = m;
}

__global__ void xhat_k(const float* __restrict__ v, const float* __restrict__ wt,
                       const float* __restrict__ bt, float* __restrict__ xhat) {
    __shared__ float lv[256];
    for (int j = threadIdx.x; j < 256; j += 256) lv[j] = v[j];
    __syncthreads();
    int idx = blockIdx.x * 256 + threadIdx.x;
    if (idx >= DD * MM) return;
    int k = idx % MM, o = idx / MM;
    float acc = bt[o];
    for (int i = 0; i < 256; ++i) acc = fmaf(lv[i], wt[(i * 256 + o) * MM + k], acc);
    xhat[idx] = acc;
}

__global__ void s1_k(const float* __restrict__ Y1, float* __restrict__ S1) {
    int idx = blockIdx.x * 256 + threadIdx.x;
    if (idx >= T_EX * 512) return;
    int c = idx % 512, t = idx / 512;
    float acc = 0.f;
    for (int m = 0; m < MM; ++m) acc += Y1[(m * T_EX + t) * 512 + c];
    S1[idx] = acc;
}

__global__ void h1_k(const float* __restrict__ Y1, const float* __restrict__ S1,
                     const float* __restrict__ bs1, ushort_t* __restrict__ h1b) {
    int idx = blockIdx.x * 256 + threadIdx.x;
    if (idx >= TM * 512) return;
    int c = idx % 512; int n = idx / 512;
    int t = n % T_EX;
    float val = S1[t * 512 + c] + bs1[c];
    if (t == 0) val -= Y1[idx];
    h1b[idx] = f2bf(lrelu(val));
}

__global__ void s2_k(const float* __restrict__ Y2, float* __restrict__ S2) {
    int idx = blockIdx.x * 256 + threadIdx.x;
    if (idx >= T_EX * 256) return;
    int c = idx % 256, t = idx / 256;
    float acc = 0.f;
    for (int m = 0; m < MM; ++m) acc += Y2[(m * T_EX + t) * 256 + c];
    S2[idx] = acc;
}

__global__ void h2_k(const float* __restrict__ Y2, const float* __restrict__ S2,
                     const float* __restrict__ bs2, float* __restrict__ h2) {
    int idx = blockIdx.x * 256 + threadIdx.x;
    if (idx >= TM * 256) return;
    int c = idx % 256; int n = idx / 256;
    int t = n % T_EX;
    float val = S2[t * 256 + c] + bs2[c];
    if (t == 0) val -= Y2[idx];
    h2[idx] = lrelu(val);
}

__global__ void v1vx_k(const float* __restrict__ h2, const float* __restrict__ xhat,
                       float* __restrict__ V1, float* __restrict__ Vx) {
    int idx = blockIdx.x * 256 + threadIdx.x;
    if (idx >= DD * MM) return;
    int m = idx % MM, d = idx / MM;
    float mx = -INFINITY;
    for (int t = 0; t < T_EX; ++t) mx = fmaxf(mx, h2[(m * T_EX + t) * 256 + d]);
    V1[idx] = mx;
    Vx[idx] = mx + xhat[idx];
}

__global__ void lin88_k(const float* __restrict__ Wg, const float* __restrict__ bg,
                        const float* __restrict__ Wh, const float* __restrict__ bh,
                        const float* __restrict__ Vin, float* __restrict__ Gout,
                        float* __restrict__ Hout) {
    int idx = blockIdx.x * 256 + threadIdx.x;
    if (idx >= DD * MM) return;
    const float* W = blockIdx.y ? Wh : Wg;
    const float* bias = blockIdx.y ? bh : bg;
    float* out = blockIdx.y ? Hout : Gout;
    int m = idx % MM, o = idx / MM;
    const float* wr = W + o * 256;
    float acc = bias[o];
    for (int i = 0; i < 256; ++i) acc = fmaf(wr[i], Vin[i * MM + m], acc);
    out[idx] = acc;
}

// ---------- fused Smat row + softmax ----------
__global__ void smsm_k(const float* __restrict__ Hh, const float* __restrict__ G,
                       float* __restrict__ A2) {
    int j = blockIdx.x;
    int tid = threadIdx.x;   // 128
    __shared__ float row[96];
    __shared__ float red[128];
    for (int i = tid; i < MM; i += 128) {
        float acc = 0.f;
        for (int c = 0; c < 256; ++c) acc = fmaf(Hh[c * MM + j], G[c * MM + i], acc);
        row[i] = acc;
    }
    __syncthreads();
    float val = (tid < MM) ? row[tid] : -INFINITY;
    red[tid] = val; __syncthreads();
    for (int s = 64; s > 0; s >>= 1) {
        if (tid < s) red[tid] = fmaxf(red[tid], red[tid + s]);
        __syncthreads();
    }
    float mx = red[0]; __syncthreads();
    float e = (tid < MM) ? expf(val - mx) : 0.f;
    red[tid] = e; __syncthreads();
    for (int s = 64; s > 0; s >>= 1) {
        if (tid < s) red[tid] += red[tid + s];
        __syncthreads();
    }
    float inv = 1.f / red[0];
    if (tid < MM) A2[j * MM + tid] = e * inv;
}

__global__ void t1_k(const float* __restrict__ V1, const float* __restrict__ wc1,
                     float* __restrict__ t1) {
    int idx = blockIdx.x * 256 + threadIdx.x;
    if (idx >= MM * 384) return;
    int c = idx % 384, m = idx / 384;
    float acc = 0.f;
    for (int d = 0; d < 256; ++d) acc = fmaf(V1[d * MM + m], wc1[d * 384 + c], acc);
    t1[idx] = acc;
}

__global__ void c1_k(const float* __restrict__ A2, const float* __restrict__ t1,
                     const float* __restrict__ bc1, float* __restrict__ c1) {
    int idx = blockIdx.x * 256 + threadIdx.x;
    if (idx >= MM * 384) return;
    int c = idx % 384, j = idx / 384;
    float acc = bc1[c];
    for (int i = 0; i < MM; ++i) acc = fmaf(A2[j * MM + i], t1[i * 384 + c], acc);
    c1[idx] = lrelu(acc);
}

__global__ void t2_k(const float* __restrict__ c1, const float* __restrict__ wc2,
                     float* __restrict__ t2) {
    int idx = blockIdx.x * 256 + threadIdx.x;
    if (idx >= MM * 256) return;
    int c = idx % 256, m = idx / 256;
    const float* cr = c1 + m * 384;
    float acc = 0.f;
    for (int d = 0; d < 384; ++d) acc = fmaf(cr[d], wc2[d * 256 + c], acc);
    t2[idx] = acc;
}

__global__ void v2_k(const float* __restrict__ A2, const float* __restrict__ t2,
                     const float* __restrict__ bc2, float* __restrict__ V2m) {
    int idx = blockIdx.x * 256 + threadIdx.x;
    if (idx >= MM * 256) return;
    int c = idx % 256, j = idx / 256;
    float acc = bc2[c];
    for (int i = 0; i < MM; ++i) acc = fmaf(A2[j * MM + i], t2[i * 256 + c], acc);
    V2m[idx] = lrelu(acc);
}

__global__ void final_k(const float* __restrict__ Xf2, const float* __restrict__ V2m,
                        float* __restrict__ out) {
    __shared__ float red[256];
    float acc = 0.f;
    for (int idx = threadIdx.x; idx < DD * MM; idx += 256)
        acc = fmaf(Xf2[idx], V2m[idx], acc);
    red[threadIdx.x] = acc; __syncthreads();
    for (int s = 128; s > 0; s >>= 1) {
        if (threadIdx.x < s) red[threadIdx.x] += red[threadIdx.x + s];
        __syncthreads();
    }
    if (threadIdx.x == 0) out[0] = red[0];
}

extern "C" void kernel_launch(void* const* d_in, const int* in_sizes, int n_in,
                              void* d_out, int out_size, void* d_ws, size_t ws_size,
                              hipStream_t stream) {
    const float* search = (const float*)d_in[0];
    const float* exemp  = (const float*)d_in[1];
    const float* aw1 = (const float*)d_in[2];  const float* ab1 = (const float*)d_in[3];
    const float* aw2 = (const float*)d_in[4];  const float* ab2 = (const float*)d_in[5];
    const float* aw3 = (const float*)d_in[6];  const float* ab3 = (const float*)d_in[7];
    const float* aw4 = (const float*)d_in[8];  const float* ab4 = (const float*)d_in[9];
    const float* aw5 = (const float*)d_in[10]; const float* ab5 = (const float*)d_in[11];
    const float* wcd = (const float*)d_in[12]; const float* bcd = (const float*)d_in[13];
    const float* wt  = (const float*)d_in[14]; const float* bt  = (const float*)d_in[15];
    const float* ws1 = (const float*)d_in[16]; const float* bs1 = (const float*)d_in[17];
    const float* ws2 = (const float*)d_in[18]; const float* bs2 = (const float*)d_in[19];
    const float* wg  = (const float*)d_in[20]; const float* bg  = (const float*)d_in[21];
    const float* wh  = (const float*)d_in[22]; const float* bh  = (const float*)d_in[23];
    const float* wc1 = (const float*)d_in[24]; const float* bc1 = (const float*)d_in[25];
    const float* wc2 = (const float*)d_in[26]; const float* bc2 = (const float*)d_in[27];

    float* ws = (float*)d_ws;
    float* R1 = ws;
    float* R2 = ws + 3870720;
    float* R3 = ws + 7544832;
    float* Wg = ws + 8628864;

    ushort_t* in1p  = (ushort_t*)R1;
    ushort_t* c1out = (ushort_t*)R2;
    ushort_t* p1out = (ushort_t*)R3;
    ushort_t* c2out = (ushort_t*)R1;
    ushort_t* p2out = (ushort_t*)R2;
    ushort_t* c3out = (ushort_t*)(R2 + 775200);
    ushort_t* c4out = (ushort_t*)R1;
    ushort_t* c5out = (ushort_t*)R3;
    ushort_t* WT    = (ushort_t*)Wg;

    // ---- conv stack (tiled weights; conv1 padded 17->18 tiles) ----
    zfill_k<<<(965500 + 255) / 256, 256, 0, stream>>>((float4*)R1, 965500);
    prep1_k<<<(BATCH * H0 * W0 + 255) / 256, 256, 0, stream>>>(search, exemp, in1p);
    wprep_k<<<(4608 + 255) / 256, 256, 0, stream>>>(aw1, WT, 11, 12, 11, 4, 3, 18, 4608);
    conv_mfma5<4, false><<<dim3(106, 1, BATCH), 256, 0, stream>>>(
        in1p, WT, ab1, c1out, HP1, WP1, 4, W1, H1 * W1, 9, 12, H1, W1, 0, 64);
    zfill_k<<<(270504 + 255) / 256, 256, 0, stream>>>((float4*)R3, 270504);
    pool_nhwc<<<(BATCH * 64 * H1P * W1P + 255) / 256, 256, 0, stream>>>(
        c1out, p1out, 64, H1, W1, H1P, W1P, 51, 39, 2);
    wprep_k<<<(38400 + 255) / 256, 256, 0, stream>>>(aw2, WT, 5, 5, 5, 64, 64, 50, 38400);
    conv_mfma5<1, true><<<dim3(26, 3, BATCH), 256, 0, stream>>>(
        p1out, WT, ab2, c2out, 51, 39, 64, W1P, H1P * W1P, 25, 5, H1P, W1P, 0, 192);
    zfill_k<<<(581400 + 255) / 256, 256, 0, stream>>>((float4*)R2, 581400);
    pool_nhwc<<<(BATCH * 192 * H2P * W2P + 255) / 256, 256, 0, stream>>>(
        c2out, p2out, 192, H1P, W1P, H2P, W2P, 25, 19, 1);
    wprep_k<<<(82944 + 255) / 256, 256, 0, stream>>>(aw3, WT, 3, 3, 3, 192, 192, 54, 82944);
    conv_mfma5<1, true><<<dim3(7, 6, BATCH), 256, 0, stream>>>(
        p2out, WT, ab3, c3out, 25, 19, 192, W2P, H2P * W2P, 27, 3, 25, 19, 1, 384);
    zfill_k<<<(258400 + 255) / 256, 256, 0, stream>>>((float4*)R1, 258400);
    wprep_k<<<(110592 + 255) / 256, 256, 0, stream>>>(aw4, WT, 3, 3, 3, 384, 384, 108, 110592);
    conv_mfma5<1, true><<<dim3(7, 4, BATCH), 256, 0, stream>>>(
        c3out, WT, ab4, c4out, 25, 19, 384, W2P, H2P * W2P, 54, 3, 25, 19, 1, 256);
    wprep_k<<<(73728 + 255) / 256, 256, 0, stream>>>(aw5, WT, 3, 3, 3, 256, 256, 72, 73728);
    conv_mfma5<1, true><<<dim3(7, 4, BATCH), 256, 0, stream>>>(
        c4out, WT, ab5, c5out, 25, 19, 256, W2P, H2P * W2P, 36, 3, H2P, W2P, 0, 256);

    // ---- tail region layout in R1 ----
    float*    P      = R1 + 2417664;
    ushort_t* PB     = (ushort_t*)(R1 + 2800640);
    ushort_t* XfPad  = (ushort_t*)(R1 + 2992128);   // rows 0 & 89 zeroed by first R1 zfill
    float*    xc     = R1 + 3003648;

    ushort_t* WS1T = (ushort_t*)Wg;
    ushort_t* WS2T = (ushort_t*)(Wg + 65536);
    ushort_t* WCDT = (ushort_t*)(Wg + 131072);
    wprep_gemm_k<<<(57344 + 255) / 256, 256, 0, stream>>>(ws1, ws2, wcd, WS1T, WS2T, WCDT);

    pool5_k<<<(BATCH * 256 * MM + 255) / 256, 256, 0, stream>>>(c5out, P, PB, XfPad);
    float* Xf2 = P;

    float* v_   = R1 + 0;
    float* xhat = R1 + 1024;
    float* Y1   = R1 + 23552;
    float* S1   = R1 + 744448;
    ushort_t* h1b = (ushort_t*)(R1 + 752640);
    float* Y2   = R1 + 1473536;
    float* S2   = R1 + 1833984;
    float* h2   = R1 + 1838080;
    float* V1   = R1 + 2198528;
    float* Vx   = R1 + 2221056;
    float* G    = R1 + 2243584;
    float* Hh   = R1 + 2266112;
    float* A2   = R1 + 2296832;
    float* t1   = R1 + 2305024;
    float* c1   = R1 + 2338816;
    float* t2   = R1 + 2372608;
    float* V2m  = R1 + 2395136;

    gemm_mfma3<0, true, false><<<dim3(2, 4), 256, 0, stream>>>(
        XfPad, WCDT, bcd, xc, 256, MM, 24, 1, MM);
    vmax_k<<<4, 64, 0, stream>>>(xc, v_);
    xhat_k<<<(DD * MM + 255) / 256, 256, 0, stream>>>(v_, wt, bt, xhat);

    gemm_mfma3<1, false, true><<<dim3(22, 8), 256, 0, stream>>>(
        PB, WS1T, nullptr, Y1, 256, TM, 8, 512, 1);
    s1_k<<<(T_EX * 512 + 255) / 256, 256, 0, stream>>>(Y1, S1);
    h1_k<<<(TM * 512 + 255) / 256, 256, 0, stream>>>(Y1, S1, bs1, h1b);
    gemm_mfma3<0, false, true><<<dim3(22, 4), 256, 0, stream>>>(
        h1b, WS2T, nullptr, Y2, 512, TM, 16, 256, 1);
    s2_k<<<(T_EX * 256 + 255) / 256, 256, 0, stream>>>(Y2, S2);
    h2_k<<<(TM * 256 + 255) / 256, 256, 0, stream>>>(Y2, S2, bs2, h2);
    v1vx_k<<<(DD * MM + 255) / 256, 256, 0, stream>>>(h2, xhat, V1, Vx);

    lin88_k<<<dim3((DD * MM + 255) / 256, 2), 256, 0, stream>>>(wg, bg, wh, bh, Vx, G, Hh);
    smsm_k<<<MM, 128, 0, stream>>>(Hh, G, A2);

    t1_k<<<(MM * 384 + 255) / 256, 256, 0, stream>>>(V1, wc1, t1);
    c1_k<<<(MM * 384 + 255) / 256, 256, 0, stream>>>(A2, t1, bc1, c1);
    t2_k<<<(MM * 256 + 255) / 256, 256, 0, stream>>>(c1, wc2, t2);
    v2_k<<<(MM * 256 + 255) / 256, 256, 0, stream>>>(A2, t2, bc2, V2m);

    final_k<<<1, 256, 0, stream>>>(Xf2, V2m, (float*)d_out);
}